// Round 1
// baseline (1374.294 us; speedup 1.0000x reference)
//
#include <hip/hip_runtime.h>
#include <hip/hip_bf16.h>

#define DIM 64
#define TPB 192   // 3 waves; LDS = 192*65*4 = 49.9 KB (under 64 KB static limit)

// nxt[j] += sum_k cur[k] * W[k*64+j]; cur = per-thread LDS row, W uniform -> s_load
__device__ __forceinline__ void gemv_acc(const float* __restrict__ W,
                                         const float* cur, float* nxt) {
    #pragma unroll 2
    for (int k = 0; k < 64; ++k) {
        float a = cur[k];
        #pragma unroll
        for (int j = 0; j < 64; ++j)
            nxt[j] = fmaf(a, W[k * 64 + j], nxt[j]);
    }
}

__global__ __launch_bounds__(TPB) void node_kernel(
    const float* __restrict__ h,
    const float* __restrict__ Wh1, const float* __restrict__ Wh2,
    const float* __restrict__ Wp1, const float* __restrict__ Wa,
    float* __restrict__ z_h, float* __restrict__ u_s, float* __restrict__ u_d,
    float* __restrict__ as_, float* __restrict__ ad_, int N)
{
    __shared__ float lds[TPB * 65];
    float* cur = &lds[threadIdx.x * 65];
    int n = blockIdx.x * TPB + threadIdx.x;
    if (n >= N) n = N - 1;   // clamp: keep control flow uniform (dup writes benign)

    const float4* hp = (const float4*)(h + (size_t)n * DIM);
    #pragma unroll
    for (int q = 0; q < 16; ++q) {
        float4 v = hp[q];
        cur[4*q+0] = v.x; cur[4*q+1] = v.y; cur[4*q+2] = v.z; cur[4*q+3] = v.w;
    }

    float nxt[64];
    // t1 = relu(h @ Wh1)
    #pragma unroll
    for (int j = 0; j < 64; ++j) nxt[j] = 0.f;
    gemv_acc(Wh1, cur, nxt);
    #pragma unroll
    for (int j = 0; j < 64; ++j) cur[j] = fmaxf(nxt[j], 0.f);

    // z_h = t1 @ Wh2
    #pragma unroll
    for (int j = 0; j < 64; ++j) nxt[j] = 0.f;
    gemv_acc(Wh2, cur, nxt);

    float asv = 0.f, adv = 0.f;
    #pragma unroll
    for (int j = 0; j < 64; ++j) {
        cur[j] = nxt[j];
        asv = fmaf(nxt[j], Wa[64 + j],  asv);
        adv = fmaf(nxt[j], Wa[128 + j], adv);
    }
    float4* zp = (float4*)(z_h + (size_t)n * DIM);
    #pragma unroll
    for (int q = 0; q < 16; ++q)
        zp[q] = make_float4(nxt[4*q+0], nxt[4*q+1], nxt[4*q+2], nxt[4*q+3]);
    as_[n] = asv;
    ad_[n] = adv;

    // u_s = z_h @ Wp1[64:128]
    #pragma unroll
    for (int j = 0; j < 64; ++j) nxt[j] = 0.f;
    gemv_acc(Wp1 + 64 * 64, cur, nxt);
    float4* usp = (float4*)(u_s + (size_t)n * DIM);
    #pragma unroll
    for (int q = 0; q < 16; ++q)
        usp[q] = make_float4(nxt[4*q+0], nxt[4*q+1], nxt[4*q+2], nxt[4*q+3]);

    // u_d = z_h @ Wp1[128:192]
    #pragma unroll
    for (int j = 0; j < 64; ++j) nxt[j] = 0.f;
    gemv_acc(Wp1 + 128 * 64, cur, nxt);
    float4* udp = (float4*)(u_d + (size_t)n * DIM);
    #pragma unroll
    for (int q = 0; q < 16; ++q)
        udp[q] = make_float4(nxt[4*q+0], nxt[4*q+1], nxt[4*q+2], nxt[4*q+3]);
}

__global__ __launch_bounds__(TPB) void edge_kernel(
    const float* __restrict__ e, const int* __restrict__ src, const int* __restrict__ dst,
    const float* __restrict__ u_s, const float* __restrict__ u_d,
    const float* __restrict__ as_, const float* __restrict__ ad_,
    const float* __restrict__ We1, const float* __restrict__ We2,
    const float* __restrict__ Wp1, const float* __restrict__ bp1,
    const float* __restrict__ Wp2, const float* __restrict__ bp2,
    const float* __restrict__ Wa,
    float* __restrict__ eproj, float* __restrict__ abuf, float* __restrict__ mbuf, int E)
{
    __shared__ float lds[TPB * 65];
    float* cur = &lds[threadIdx.x * 65];
    int i = blockIdx.x * TPB + threadIdx.x;
    if (i >= E) i = E - 1;   // clamp (dup edge writes same values; atomicMax idempotent)

    int sn = src[i], dn = dst[i];

    const float4* ep = (const float4*)(e + (size_t)i * DIM);
    #pragma unroll
    for (int q = 0; q < 16; ++q) {
        float4 v = ep[q];
        cur[4*q+0] = v.x; cur[4*q+1] = v.y; cur[4*q+2] = v.z; cur[4*q+3] = v.w;
    }

    float nxt[64];
    // t = relu(e @ We1)
    #pragma unroll
    for (int j = 0; j < 64; ++j) nxt[j] = 0.f;
    gemv_acc(We1, cur, nxt);
    #pragma unroll
    for (int j = 0; j < 64; ++j) cur[j] = fmaxf(nxt[j], 0.f);

    // z_e = t @ We2 ; ae = z_e . Wa[0:64]
    #pragma unroll
    for (int j = 0; j < 64; ++j) nxt[j] = 0.f;
    gemv_acc(We2, cur, nxt);
    float ae = 0.f;
    #pragma unroll
    for (int j = 0; j < 64; ++j) {
        cur[j] = nxt[j];
        ae = fmaf(nxt[j], Wa[j], ae);
    }

    // attention score a = relu(ae + as[src] + ad[dst]); running segment max
    float aval = fmaxf(ae + as_[sn] + ad_[dn], 0.f);
    abuf[i] = aval;
    atomicMax((int*)mbuf + dn, __float_as_int(aval));   // valid: aval >= 0, m init 0

    // t2 = relu(z_e @ Wp1[0:64] + u_s[src] + u_d[dst] + bp1)
    const float4* usp = (const float4*)(u_s + (size_t)sn * DIM);
    const float4* udp = (const float4*)(u_d + (size_t)dn * DIM);
    const float4* bp  = (const float4*)bp1;
    #pragma unroll
    for (int q = 0; q < 16; ++q) {
        float4 a = usp[q], b = udp[q], c = bp[q];
        nxt[4*q+0] = a.x + b.x + c.x;
        nxt[4*q+1] = a.y + b.y + c.y;
        nxt[4*q+2] = a.z + b.z + c.z;
        nxt[4*q+3] = a.w + b.w + c.w;
    }
    gemv_acc(Wp1, cur, nxt);
    #pragma unroll
    for (int j = 0; j < 64; ++j) cur[j] = fmaxf(nxt[j], 0.f);

    // e_proj = t2 @ Wp2 + bp2 ; out = relu(e_proj)
    const float4* b2 = (const float4*)bp2;
    #pragma unroll
    for (int q = 0; q < 16; ++q) {
        float4 c = b2[q];
        nxt[4*q+0] = c.x; nxt[4*q+1] = c.y; nxt[4*q+2] = c.z; nxt[4*q+3] = c.w;
    }
    gemv_acc(Wp2, cur, nxt);
    float4* op = (float4*)(eproj + (size_t)i * DIM);
    #pragma unroll
    for (int q = 0; q < 16; ++q)
        op[q] = make_float4(fmaxf(nxt[4*q+0], 0.f), fmaxf(nxt[4*q+1], 0.f),
                            fmaxf(nxt[4*q+2], 0.f), fmaxf(nxt[4*q+3], 0.f));
}

__global__ __launch_bounds__(256) void k_expsum(
    const float* __restrict__ mbuf, const int* __restrict__ dst,
    float* __restrict__ abuf, float* __restrict__ sden, int E)
{
    int i = blockIdx.x * 256 + threadIdx.x;
    if (i < E) {
        int d = dst[i];
        float ex = expf(abuf[i] - mbuf[d]);
        abuf[i] = ex;
        atomicAdd(&sden[d], ex);
    }
}

__global__ __launch_bounds__(256) void k_scatter(
    const float* __restrict__ abuf, const float* __restrict__ sden,
    const int* __restrict__ src, const int* __restrict__ dst,
    const float* __restrict__ z_h, float* __restrict__ hout, int E)
{
    int gid = blockIdx.x * 256 + threadIdx.x;
    int i = gid >> 4;
    if (i < E) {
        int f = (gid & 15) * 4;
        int sn = src[i], dn = dst[i];
        float alpha = abuf[i] / fmaxf(sden[dn], 1e-9f);
        const float4 v = *(const float4*)(z_h + (size_t)sn * DIM + f);
        float* o = hout + (size_t)dn * DIM + f;
        atomicAdd(o + 0, alpha * v.x);
        atomicAdd(o + 1, alpha * v.y);
        atomicAdd(o + 2, alpha * v.z);
        atomicAdd(o + 3, alpha * v.w);
    }
}

__global__ __launch_bounds__(256) void k_relu4(float* __restrict__ x, int n4)
{
    int i = blockIdx.x * 256 + threadIdx.x;
    if (i < n4) {
        float4* p = (float4*)x + i;
        float4 v = *p;
        v.x = fmaxf(v.x, 0.f); v.y = fmaxf(v.y, 0.f);
        v.z = fmaxf(v.z, 0.f); v.w = fmaxf(v.w, 0.f);
        *p = v;
    }
}

extern "C" void kernel_launch(void* const* d_in, const int* in_sizes, int n_in,
                              void* d_out, int out_size, void* d_ws, size_t ws_size,
                              hipStream_t stream)
{
    const float* h   = (const float*)d_in[0];
    const float* e   = (const float*)d_in[1];
    const int*   src = (const int*)d_in[2];
    const int*   dst = (const int*)d_in[3];
    const float* Wh1 = (const float*)d_in[4];
    const float* Wh2 = (const float*)d_in[5];
    const float* We1 = (const float*)d_in[6];
    const float* We2 = (const float*)d_in[7];
    const float* Wp1 = (const float*)d_in[8];
    const float* bp1 = (const float*)d_in[9];
    const float* Wp2 = (const float*)d_in[10];
    const float* bp2 = (const float*)d_in[11];
    const float* Wa  = (const float*)d_in[12];

    const int N = in_sizes[0] / DIM;
    const int E = in_sizes[1] / DIM;

    float* ws   = (float*)d_ws;
    float* z_h  = ws;  ws += (size_t)N * DIM;
    float* u_s  = ws;  ws += (size_t)N * DIM;
    float* u_d  = ws;  ws += (size_t)N * DIM;
    float* as_  = ws;  ws += N;
    float* ad_  = ws;  ws += N;
    float* abuf = ws;  ws += E;
    float* mbuf = ws;  ws += N;
    float* sden = ws;  ws += N;   // mbuf & sden adjacent -> single memset

    float* hout  = (float*)d_out;
    float* eproj = hout + (size_t)N * DIM;

    hipMemsetAsync(hout, 0, (size_t)N * DIM * sizeof(float), stream);
    hipMemsetAsync(mbuf, 0, (size_t)2 * N * sizeof(float), stream);

    node_kernel<<<(N + TPB - 1) / TPB, TPB, 0, stream>>>(
        h, Wh1, Wh2, Wp1, Wa, z_h, u_s, u_d, as_, ad_, N);

    edge_kernel<<<(E + TPB - 1) / TPB, TPB, 0, stream>>>(
        e, src, dst, u_s, u_d, as_, ad_, We1, We2, Wp1, bp1, Wp2, bp2, Wa,
        eproj, abuf, mbuf, E);

    k_expsum<<<(E + 255) / 256, 256, 0, stream>>>(mbuf, dst, abuf, sden, E);

    k_scatter<<<((E * 16) + 255) / 256, 256, 0, stream>>>(
        abuf, sden, src, dst, z_h, hout, E);

    k_relu4<<<((N * DIM / 4) + 255) / 256, 256, 0, stream>>>(hout, N * DIM / 4);
}

// Round 2
// 982.718 us; speedup vs baseline: 1.3985x; 1.3985x over previous
//
#include <hip/hip_runtime.h>
#include <hip/hip_bf16.h>

#define DIM 64
#define TPB 192   // 3 waves; LDS = 192*65*4 = 49.9 KB

// nxt[j] += sum_k cur[k] * W[k*64+j]; cur = per-thread LDS row, W uniform -> s_load
__device__ __forceinline__ void gemv_acc(const float* __restrict__ W,
                                         const float* cur, float* nxt) {
    #pragma unroll 2
    for (int k = 0; k < 64; ++k) {
        float a = cur[k];
        #pragma unroll
        for (int j = 0; j < 64; ++j)
            nxt[j] = fmaf(a, W[k * 64 + j], nxt[j]);
    }
}

__global__ __launch_bounds__(TPB) void node_kernel(
    const float* __restrict__ h,
    const float* __restrict__ Wh1, const float* __restrict__ Wh2,
    const float* __restrict__ Wp1, const float* __restrict__ Wa,
    float* __restrict__ z_h, float* __restrict__ u_s, float* __restrict__ u_d,
    float* __restrict__ as_, float* __restrict__ ad_, int N)
{
    __shared__ float lds[TPB * 65];
    float* cur = &lds[threadIdx.x * 65];
    int n = blockIdx.x * TPB + threadIdx.x;
    if (n >= N) n = N - 1;   // clamp: keep control flow uniform (dup writes benign)

    const float4* hp = (const float4*)(h + (size_t)n * DIM);
    #pragma unroll
    for (int q = 0; q < 16; ++q) {
        float4 v = hp[q];
        cur[4*q+0] = v.x; cur[4*q+1] = v.y; cur[4*q+2] = v.z; cur[4*q+3] = v.w;
    }

    float nxt[64];
    // t1 = relu(h @ Wh1)
    #pragma unroll
    for (int j = 0; j < 64; ++j) nxt[j] = 0.f;
    gemv_acc(Wh1, cur, nxt);
    #pragma unroll
    for (int j = 0; j < 64; ++j) cur[j] = fmaxf(nxt[j], 0.f);

    // z_h = t1 @ Wh2
    #pragma unroll
    for (int j = 0; j < 64; ++j) nxt[j] = 0.f;
    gemv_acc(Wh2, cur, nxt);

    float asv = 0.f, adv = 0.f;
    #pragma unroll
    for (int j = 0; j < 64; ++j) {
        cur[j] = nxt[j];
        asv = fmaf(nxt[j], Wa[64 + j],  asv);
        adv = fmaf(nxt[j], Wa[128 + j], adv);
    }
    float4* zp = (float4*)(z_h + (size_t)n * DIM);
    #pragma unroll
    for (int q = 0; q < 16; ++q)
        zp[q] = make_float4(nxt[4*q+0], nxt[4*q+1], nxt[4*q+2], nxt[4*q+3]);
    as_[n] = asv;
    ad_[n] = adv;

    // u_s = z_h @ Wp1[64:128]
    #pragma unroll
    for (int j = 0; j < 64; ++j) nxt[j] = 0.f;
    gemv_acc(Wp1 + 64 * 64, cur, nxt);
    float4* usp = (float4*)(u_s + (size_t)n * DIM);
    #pragma unroll
    for (int q = 0; q < 16; ++q)
        usp[q] = make_float4(nxt[4*q+0], nxt[4*q+1], nxt[4*q+2], nxt[4*q+3]);

    // u_d = z_h @ Wp1[128:192]
    #pragma unroll
    for (int j = 0; j < 64; ++j) nxt[j] = 0.f;
    gemv_acc(Wp1 + 128 * 64, cur, nxt);
    float4* udp = (float4*)(u_d + (size_t)n * DIM);
    #pragma unroll
    for (int q = 0; q < 16; ++q)
        udp[q] = make_float4(nxt[4*q+0], nxt[4*q+1], nxt[4*q+2], nxt[4*q+3]);
}

__global__ __launch_bounds__(TPB) void edge_kernel(
    const float* __restrict__ e, const int* __restrict__ src, const int* __restrict__ dst,
    const float* __restrict__ u_s, const float* __restrict__ u_d,
    const float* __restrict__ as_, const float* __restrict__ ad_,
    const float* __restrict__ We1, const float* __restrict__ We2,
    const float* __restrict__ Wp1, const float* __restrict__ bp1,
    const float* __restrict__ Wp2, const float* __restrict__ bp2,
    const float* __restrict__ Wa,
    float* __restrict__ eproj, float* __restrict__ abuf, int E)
{
    __shared__ float lds[TPB * 65];
    float* cur = &lds[threadIdx.x * 65];
    int i = blockIdx.x * TPB + threadIdx.x;
    if (i >= E) i = E - 1;   // clamp (dup edge writes same values)

    int sn = src[i], dn = dst[i];

    const float4* ep = (const float4*)(e + (size_t)i * DIM);
    #pragma unroll
    for (int q = 0; q < 16; ++q) {
        float4 v = ep[q];
        cur[4*q+0] = v.x; cur[4*q+1] = v.y; cur[4*q+2] = v.z; cur[4*q+3] = v.w;
    }

    float nxt[64];
    // t = relu(e @ We1)
    #pragma unroll
    for (int j = 0; j < 64; ++j) nxt[j] = 0.f;
    gemv_acc(We1, cur, nxt);
    #pragma unroll
    for (int j = 0; j < 64; ++j) cur[j] = fmaxf(nxt[j], 0.f);

    // z_e = t @ We2 ; ae = z_e . Wa[0:64]
    #pragma unroll
    for (int j = 0; j < 64; ++j) nxt[j] = 0.f;
    gemv_acc(We2, cur, nxt);
    float ae = 0.f;
    #pragma unroll
    for (int j = 0; j < 64; ++j) {
        cur[j] = nxt[j];
        ae = fmaf(nxt[j], Wa[j], ae);
    }

    // attention score a = relu(ae + as[src] + ad[dst])
    float aval = fmaxf(ae + as_[sn] + ad_[dn], 0.f);
    abuf[i] = aval;

    // t2 = relu(z_e @ Wp1[0:64] + u_s[src] + u_d[dst] + bp1)
    const float4* usp = (const float4*)(u_s + (size_t)sn * DIM);
    const float4* udp = (const float4*)(u_d + (size_t)dn * DIM);
    const float4* bp  = (const float4*)bp1;
    #pragma unroll
    for (int q = 0; q < 16; ++q) {
        float4 a = usp[q], b = udp[q], c = bp[q];
        nxt[4*q+0] = a.x + b.x + c.x;
        nxt[4*q+1] = a.y + b.y + c.y;
        nxt[4*q+2] = a.z + b.z + c.z;
        nxt[4*q+3] = a.w + b.w + c.w;
    }
    gemv_acc(Wp1, cur, nxt);
    #pragma unroll
    for (int j = 0; j < 64; ++j) cur[j] = fmaxf(nxt[j], 0.f);

    // e_proj = t2 @ Wp2 + bp2 ; out = relu(e_proj)
    const float4* b2 = (const float4*)bp2;
    #pragma unroll
    for (int q = 0; q < 16; ++q) {
        float4 c = b2[q];
        nxt[4*q+0] = c.x; nxt[4*q+1] = c.y; nxt[4*q+2] = c.z; nxt[4*q+3] = c.w;
    }
    gemv_acc(Wp2, cur, nxt);
    float4* op = (float4*)(eproj + (size_t)i * DIM);
    #pragma unroll
    for (int q = 0; q < 16; ++q)
        op[q] = make_float4(fmaxf(nxt[4*q+0], 0.f), fmaxf(nxt[4*q+1], 0.f),
                            fmaxf(nxt[4*q+2], 0.f), fmaxf(nxt[4*q+3], 0.f));
}

// ---- CSR build: histogram -> scan -> fill ----

__global__ __launch_bounds__(256) void k_hist(
    const int* __restrict__ dst, int* __restrict__ cnt, int E)
{
    int i = blockIdx.x * 256 + threadIdx.x;
    if (i < E) atomicAdd(&cnt[dst[i]], 1);
}

#define SCAN_T 1024
__global__ __launch_bounds__(SCAN_T) void k_scan(
    const int* __restrict__ cnt, int* __restrict__ ofs, int* __restrict__ cursor, int N)
{
    __shared__ int part[SCAN_T];
    int t = threadIdx.x;
    int chunk = (N + SCAN_T - 1) / SCAN_T;
    int b = t * chunk, e_ = min(b + chunk, N);
    int s = 0;
    for (int i = b; i < e_; ++i) s += cnt[i];
    part[t] = s;
    __syncthreads();
    for (int off = 1; off < SCAN_T; off <<= 1) {
        int v = (t >= off) ? part[t - off] : 0;
        __syncthreads();
        part[t] += v;
        __syncthreads();
    }
    int run = (t == 0) ? 0 : part[t - 1];
    for (int i = b; i < e_; ++i) {
        ofs[i] = run; cursor[i] = run;
        run += cnt[i];
    }
}

__global__ __launch_bounds__(256) void k_fill(
    const int* __restrict__ dst, int* __restrict__ cursor, int* __restrict__ eidx, int E)
{
    int i = blockIdx.x * 256 + threadIdx.x;
    if (i < E) {
        int p = atomicAdd(&cursor[dst[i]], 1);
        eidx[p] = i;
    }
}

// ---- fused segment softmax + weighted gather-sum: one wave per node ----
__global__ __launch_bounds__(256) void k_aggregate(
    const float* __restrict__ abuf, const int* __restrict__ eidx,
    const int* __restrict__ ofs, const int* __restrict__ cnt,
    const int* __restrict__ src, const float* __restrict__ z_h,
    float* __restrict__ hout, int N)
{
    int wid  = (blockIdx.x * 256 + threadIdx.x) >> 6;
    int lane = threadIdx.x & 63;
    if (wid >= N) return;

    int begin = ofs[wid];
    int deg   = cnt[wid];

    // segment max (scores are relu'd >= 0, so init 0 matches reference's
    // where(isfinite, m, 0) semantics exactly)
    float m = 0.f;
    for (int k = lane; k < deg; k += 64) m = fmaxf(m, abuf[eidx[begin + k]]);
    #pragma unroll
    for (int off = 32; off; off >>= 1) m = fmaxf(m, __shfl_xor(m, off));

    // segment sum of exp(a - m)
    float s = 0.f;
    for (int k = lane; k < deg; k += 64) s += expf(abuf[eidx[begin + k]] - m);
    #pragma unroll
    for (int off = 32; off; off >>= 1) s += __shfl_xor(s, off);

    float inv_s = 1.0f / fmaxf(s, 1e-9f);

    // weighted gather-sum: lane j owns feature j
    float acc = 0.f;
    for (int k = 0; k < deg; ++k) {
        int eid   = eidx[begin + k];
        float alpha = expf(abuf[eid] - m) * inv_s;   // broadcast loads, redundant exp
        acc = fmaf(alpha, z_h[(size_t)src[eid] * DIM + lane], acc);
    }
    hout[(size_t)wid * DIM + lane] = fmaxf(acc, 0.f);
}

extern "C" void kernel_launch(void* const* d_in, const int* in_sizes, int n_in,
                              void* d_out, int out_size, void* d_ws, size_t ws_size,
                              hipStream_t stream)
{
    const float* h   = (const float*)d_in[0];
    const float* e   = (const float*)d_in[1];
    const int*   src = (const int*)d_in[2];
    const int*   dst = (const int*)d_in[3];
    const float* Wh1 = (const float*)d_in[4];
    const float* Wh2 = (const float*)d_in[5];
    const float* We1 = (const float*)d_in[6];
    const float* We2 = (const float*)d_in[7];
    const float* Wp1 = (const float*)d_in[8];
    const float* bp1 = (const float*)d_in[9];
    const float* Wp2 = (const float*)d_in[10];
    const float* bp2 = (const float*)d_in[11];
    const float* Wa  = (const float*)d_in[12];

    const int N = in_sizes[0] / DIM;
    const int E = in_sizes[1] / DIM;

    float* ws   = (float*)d_ws;
    float* z_h  = ws;  ws += (size_t)N * DIM;
    float* u_s  = ws;  ws += (size_t)N * DIM;
    float* u_d  = ws;  ws += (size_t)N * DIM;
    float* as_  = ws;  ws += N;
    float* ad_  = ws;  ws += N;
    float* abuf = ws;  ws += E;
    int* cnt    = (int*)ws;  ws += N;
    int* ofs    = (int*)ws;  ws += N;
    int* cursor = (int*)ws;  ws += N;
    int* eidx   = (int*)ws;  ws += E;

    float* hout  = (float*)d_out;
    float* eproj = hout + (size_t)N * DIM;

    hipMemsetAsync(cnt, 0, (size_t)N * sizeof(int), stream);

    node_kernel<<<(N + TPB - 1) / TPB, TPB, 0, stream>>>(
        h, Wh1, Wh2, Wp1, Wa, z_h, u_s, u_d, as_, ad_, N);

    edge_kernel<<<(E + TPB - 1) / TPB, TPB, 0, stream>>>(
        e, src, dst, u_s, u_d, as_, ad_, We1, We2, Wp1, bp1, Wp2, bp2, Wa,
        eproj, abuf, E);

    k_hist<<<(E + 255) / 256, 256, 0, stream>>>(dst, cnt, E);
    k_scan<<<1, SCAN_T, 0, stream>>>(cnt, ofs, cursor, N);
    k_fill<<<(E + 255) / 256, 256, 0, stream>>>(dst, cursor, eidx, E);

    k_aggregate<<<((N * 64) + 255) / 256, 256, 0, stream>>>(
        abuf, eidx, ofs, cnt, src, z_h, hout, N);
}

// Round 3
// 663.520 us; speedup vs baseline: 2.0712x; 1.4811x over previous
//
#include <hip/hip_runtime.h>
#include <hip/hip_bf16.h>

#define DIM 64
#define TPB 192
#define BM 128

typedef __attribute__((ext_vector_type(8))) short bf16x8;
typedef __attribute__((ext_vector_type(4))) float f32x4;

__device__ __forceinline__ unsigned short f2bf(float x) {
    unsigned u = __float_as_uint(x);
    return (unsigned short)((u + 0x7FFFu + ((u >> 16) & 1u)) >> 16);   // RNE
}
__device__ __forceinline__ float bf2f(unsigned short b) {
    return __uint_as_float(((unsigned)b) << 16);
}
__device__ __forceinline__ void split8(float4 a, float4 b, bf16x8& hi, bf16x8& lo) {
    float v[8] = {a.x, a.y, a.z, a.w, b.x, b.y, b.z, b.w};
    #pragma unroll
    for (int i = 0; i < 8; ++i) {
        unsigned short h = f2bf(v[i]);
        hi[i] = (short)h;
        lo[i] = (short)f2bf(v[i] - bf2f(h));
    }
}
// XOR-swizzle (T2): byte address within the act tile; row stride 256B
__device__ __forceinline__ int swz(int row, int colbyte) {
    return row * 256 + (colbyte ^ ((row & 7) << 4));
}

// ---- weight prep: split fp32 weights into hi/lo bf16, pre-arranged in MFMA
// B-fragment order: wbuf[layer][kt][nt][lane][e], k = kt*32 + (lane>>4)*8 + e,
// n = nt*16 + (lane&15). (k-map must only match the A-side k-map.)
__global__ __launch_bounds__(256) void k_prep(
    const float* __restrict__ We1, const float* __restrict__ We2,
    const float* __restrict__ Wp1, const float* __restrict__ Wp2,
    unsigned short* __restrict__ whi, unsigned short* __restrict__ wlo)
{
    int t = blockIdx.x * 256 + threadIdx.x;     // 0..16383
    int e_ = t & 7, lane = (t >> 3) & 63, frag = (t >> 9) & 7, layer = t >> 12;
    int kt = frag >> 2, nt = frag & 3;
    int k = kt * 32 + ((lane >> 4) * 8) + e_;
    int n = nt * 16 + (lane & 15);
    const float* W = layer == 0 ? We1 : layer == 1 ? We2 : layer == 2 ? Wp1 : Wp2;
    float w = W[k * 64 + n];
    unsigned short h = f2bf(w);
    whi[t] = h;
    wlo[t] = f2bf(w - bf2f(h));
}

// ---- node precompute (fp32 GEMV; only 1/16 of edge work) ----
__device__ __forceinline__ void gemv_acc(const float* __restrict__ W,
                                         const float* cur, float* nxt) {
    #pragma unroll 2
    for (int k = 0; k < 64; ++k) {
        float a = cur[k];
        #pragma unroll
        for (int j = 0; j < 64; ++j)
            nxt[j] = fmaf(a, W[k * 64 + j], nxt[j]);
    }
}

__global__ __launch_bounds__(TPB) void node_kernel(
    const float* __restrict__ h,
    const float* __restrict__ Wh1, const float* __restrict__ Wh2,
    const float* __restrict__ Wp1, const float* __restrict__ Wa,
    float* __restrict__ z_h, float* __restrict__ u_s, float* __restrict__ u_d,
    float* __restrict__ as_, float* __restrict__ ad_, int N)
{
    __shared__ float ldsn[TPB * 65];
    float* cur = &ldsn[threadIdx.x * 65];
    int n = blockIdx.x * TPB + threadIdx.x;
    if (n >= N) n = N - 1;

    const float4* hp = (const float4*)(h + (size_t)n * DIM);
    #pragma unroll
    for (int q = 0; q < 16; ++q) {
        float4 v = hp[q];
        cur[4*q+0] = v.x; cur[4*q+1] = v.y; cur[4*q+2] = v.z; cur[4*q+3] = v.w;
    }

    float nxt[64];
    #pragma unroll
    for (int j = 0; j < 64; ++j) nxt[j] = 0.f;
    gemv_acc(Wh1, cur, nxt);
    #pragma unroll
    for (int j = 0; j < 64; ++j) cur[j] = fmaxf(nxt[j], 0.f);

    #pragma unroll
    for (int j = 0; j < 64; ++j) nxt[j] = 0.f;
    gemv_acc(Wh2, cur, nxt);

    float asv = 0.f, adv = 0.f;
    #pragma unroll
    for (int j = 0; j < 64; ++j) {
        cur[j] = nxt[j];
        asv = fmaf(nxt[j], Wa[64 + j],  asv);
        adv = fmaf(nxt[j], Wa[128 + j], adv);
    }
    float4* zp = (float4*)(z_h + (size_t)n * DIM);
    #pragma unroll
    for (int q = 0; q < 16; ++q)
        zp[q] = make_float4(nxt[4*q+0], nxt[4*q+1], nxt[4*q+2], nxt[4*q+3]);
    as_[n] = asv;
    ad_[n] = adv;

    #pragma unroll
    for (int j = 0; j < 64; ++j) nxt[j] = 0.f;
    gemv_acc(Wp1 + 64 * 64, cur, nxt);
    float4* usp = (float4*)(u_s + (size_t)n * DIM);
    #pragma unroll
    for (int q = 0; q < 16; ++q)
        usp[q] = make_float4(nxt[4*q+0], nxt[4*q+1], nxt[4*q+2], nxt[4*q+3]);

    #pragma unroll
    for (int j = 0; j < 64; ++j) nxt[j] = 0.f;
    gemv_acc(Wp1 + 128 * 64, cur, nxt);
    float4* udp = (float4*)(u_d + (size_t)n * DIM);
    #pragma unroll
    for (int q = 0; q < 16; ++q)
        udp[q] = make_float4(nxt[4*q+0], nxt[4*q+1], nxt[4*q+2], nxt[4*q+3]);
}

// ---- edge pipeline: split-bf16 MFMA chain, 128 edges/block, 4 waves x 32 rows.
// Rows are wave-private -> NO barriers; LDS act tile only shuffles C-layout ->
// A-layout between layers. 3-term MFMA (hi*hi + hi*lo + lo*hi) ~ fp32 precision.
__global__ __launch_bounds__(256) void edge_mfma(
    const float* __restrict__ e, const int* __restrict__ src, const int* __restrict__ dst,
    const float* __restrict__ u_s, const float* __restrict__ u_d,
    const float* __restrict__ as_, const float* __restrict__ ad_,
    const unsigned short* __restrict__ whi, const unsigned short* __restrict__ wlo,
    const float* __restrict__ Wa, const float* __restrict__ bp1, const float* __restrict__ bp2,
    float* __restrict__ eproj, float* __restrict__ abuf, int E)
{
    __shared__ float act[BM * 64];          // 32 KB, swizzled, wave-private rows
    char* lds = (char*)act;
    const int lane  = threadIdx.x & 63;
    const int wave  = threadIdx.x >> 6;
    const int wrow0 = wave * 32;
    const long edge0 = (long)blockIdx.x * BM;
    const int g   = lane >> 4;
    const int c15 = lane & 15;

    // per-row src/dst for this wave's C-layout rows: row = wrow0 + mt*16 + g*4 + rr
    int sn[2][4], dn[2][4];
    #pragma unroll
    for (int mt = 0; mt < 2; ++mt)
        #pragma unroll
        for (int rr = 0; rr < 4; ++rr) {
            long er = edge0 + wrow0 + mt * 16 + g * 4 + rr; if (er >= E) er = E - 1;
            sn[mt][rr] = src[er]; dn[mt][rr] = dst[er];
        }

    float waf[4], b1f[4], b2f[4];
    #pragma unroll
    for (int nt = 0; nt < 4; ++nt) {
        waf[nt] = Wa[nt * 16 + c15];
        b1f[nt] = bp1[nt * 16 + c15];
        b2f[nt] = bp2[nt * 16 + c15];
    }

    // prefetch per-edge gathers early (used at L3 / attention)
    float uv[2][4][4], asv[2][4];
    #pragma unroll
    for (int mt = 0; mt < 2; ++mt)
        #pragma unroll
        for (int rr = 0; rr < 4; ++rr) {
            const float* us = u_s + (size_t)sn[mt][rr] * DIM;
            const float* ud = u_d + (size_t)dn[mt][rr] * DIM;
            #pragma unroll
            for (int nt = 0; nt < 4; ++nt)
                uv[mt][nt][rr] = us[nt * 16 + c15] + ud[nt * 16 + c15] + b1f[nt];
            asv[mt][rr] = as_[sn[mt][rr]] + ad_[dn[mt][rr]];
        }

    f32x4 acc[2][4];
    auto zacc = [&]() {
        #pragma unroll
        for (int mt = 0; mt < 2; ++mt)
            #pragma unroll
            for (int nt = 0; nt < 4; ++nt)
                #pragma unroll
                for (int rr = 0; rr < 4; ++rr) acc[mt][nt][rr] = 0.f;
    };

    auto mfma_layer = [&](int layer) {
        #pragma unroll
        for (int kt = 0; kt < 2; ++kt) {
            bf16x8 ah[2], al[2];
            #pragma unroll
            for (int mt = 0; mt < 2; ++mt) {
                float4 a0, a1;
                if (layer == 0) {          // A directly from global e
                    long er = edge0 + wrow0 + mt * 16 + c15; if (er >= E) er = E - 1;
                    const float* p = e + er * 64 + kt * 32 + g * 8;
                    a0 = *(const float4*)p;
                    a1 = *(const float4*)(p + 4);
                } else {                    // A from swizzled LDS act tile
                    int row = wrow0 + mt * 16 + c15;
                    int cb  = kt * 128 + g * 32;
                    a0 = *(const float4*)(lds + swz(row, cb));
                    a1 = *(const float4*)(lds + swz(row, cb + 16));
                }
                split8(a0, a1, ah[mt], al[mt]);
            }
            #pragma unroll
            for (int nt = 0; nt < 4; ++nt) {
                int fo = ((layer * 8 + kt * 4 + nt) * 64 + lane) * 8;
                bf16x8 bh = *(const bf16x8*)(whi + fo);
                bf16x8 bl = *(const bf16x8*)(wlo + fo);
                #pragma unroll
                for (int mt = 0; mt < 2; ++mt) {
                    acc[mt][nt] = __builtin_amdgcn_mfma_f32_16x16x32_bf16(ah[mt], bh, acc[mt][nt], 0, 0, 0);
                    acc[mt][nt] = __builtin_amdgcn_mfma_f32_16x16x32_bf16(ah[mt], bl, acc[mt][nt], 0, 0, 0);
                    acc[mt][nt] = __builtin_amdgcn_mfma_f32_16x16x32_bf16(al[mt], bh, acc[mt][nt], 0, 0, 0);
                }
            }
        }
    };

    auto writeback = [&](bool relu) {
        #pragma unroll
        for (int mt = 0; mt < 2; ++mt)
            #pragma unroll
            for (int nt = 0; nt < 4; ++nt)
                #pragma unroll
                for (int rr = 0; rr < 4; ++rr) {
                    int row  = wrow0 + mt * 16 + g * 4 + rr;
                    int colb = (nt * 16 + c15) * 4;
                    float v = acc[mt][nt][rr];
                    if (relu) v = fmaxf(v, 0.f);
                    *(float*)(lds + swz(row, colb)) = v;
                }
    };

    // L1: t1 = relu(e @ We1)
    zacc(); mfma_layer(0); writeback(true);
    // L2: z_e = t1 @ We2 (no relu)
    zacc(); mfma_layer(1);

    // attention score from z_e C-frags: ae = z_e . Wa[0:64]
    #pragma unroll
    for (int mt = 0; mt < 2; ++mt) {
        float part[4];
        #pragma unroll
        for (int rr = 0; rr < 4; ++rr)
            part[rr] = acc[mt][0][rr] * waf[0] + acc[mt][1][rr] * waf[1]
                     + acc[mt][2][rr] * waf[2] + acc[mt][3][rr] * waf[3];
        #pragma unroll
        for (int off = 1; off < 16; off <<= 1)
            #pragma unroll
            for (int rr = 0; rr < 4; ++rr) part[rr] += __shfl_xor(part[rr], off);
        if (c15 == 0) {
            #pragma unroll
            for (int rr = 0; rr < 4; ++rr) {
                long er = edge0 + wrow0 + mt * 16 + g * 4 + rr; if (er >= E) er = E - 1;
                abuf[er] = fmaxf(part[rr] + asv[mt][rr], 0.f);
            }
        }
    }
    writeback(false);    // z_e -> LDS

    // L3: t2 = relu(z_e @ Wp1[0:64] + u_s[src] + u_d[dst] + bp1)
    zacc(); mfma_layer(2);
    #pragma unroll
    for (int mt = 0; mt < 2; ++mt)
        #pragma unroll
        for (int nt = 0; nt < 4; ++nt)
            #pragma unroll
            for (int rr = 0; rr < 4; ++rr)
                acc[mt][nt][rr] += uv[mt][nt][rr];
    writeback(true);

    // L4: eproj = relu(t2 @ Wp2 + bp2) -> global, straight from C frags
    zacc(); mfma_layer(3);
    #pragma unroll
    for (int mt = 0; mt < 2; ++mt)
        #pragma unroll
        for (int nt = 0; nt < 4; ++nt)
            #pragma unroll
            for (int rr = 0; rr < 4; ++rr) {
                long er = edge0 + wrow0 + mt * 16 + g * 4 + rr; if (er >= E) er = E - 1;
                eproj[er * 64 + nt * 16 + c15] = fmaxf(acc[mt][nt][rr] + b2f[nt], 0.f);
            }
}

// ---- CSR build: histogram -> scan -> fill ----
__global__ __launch_bounds__(256) void k_hist(
    const int* __restrict__ dst, int* __restrict__ cnt, int E)
{
    int i = blockIdx.x * 256 + threadIdx.x;
    if (i < E) atomicAdd(&cnt[dst[i]], 1);
}

#define SCAN_T 1024
__global__ __launch_bounds__(SCAN_T) void k_scan(
    const int* __restrict__ cnt, int* __restrict__ ofs, int* __restrict__ cursor, int N)
{
    __shared__ int part[SCAN_T];
    int t = threadIdx.x;
    int chunk = (N + SCAN_T - 1) / SCAN_T;
    int b = t * chunk, e_ = min(b + chunk, N);
    int s = 0;
    for (int i = b; i < e_; ++i) s += cnt[i];
    part[t] = s;
    __syncthreads();
    for (int off = 1; off < SCAN_T; off <<= 1) {
        int v = (t >= off) ? part[t - off] : 0;
        __syncthreads();
        part[t] += v;
        __syncthreads();
    }
    int run = (t == 0) ? 0 : part[t - 1];
    for (int i = b; i < e_; ++i) {
        ofs[i] = run; cursor[i] = run;
        run += cnt[i];
    }
}

__global__ __launch_bounds__(256) void k_fill(
    const int* __restrict__ dst, int* __restrict__ cursor, int* __restrict__ eidx, int E)
{
    int i = blockIdx.x * 256 + threadIdx.x;
    if (i < E) {
        int p = atomicAdd(&cursor[dst[i]], 1);
        eidx[p] = i;
    }
}

// ---- fused segment softmax + weighted gather-sum: one wave per node ----
__global__ __launch_bounds__(256) void k_aggregate(
    const float* __restrict__ abuf, const int* __restrict__ eidx,
    const int* __restrict__ ofs, const int* __restrict__ cnt,
    const int* __restrict__ src, const float* __restrict__ z_h,
    float* __restrict__ hout, int N)
{
    int wid  = (blockIdx.x * 256 + threadIdx.x) >> 6;
    int lane = threadIdx.x & 63;
    if (wid >= N) return;

    int begin = ofs[wid];
    int deg   = cnt[wid];

    float m = 0.f;
    for (int k = lane; k < deg; k += 64) m = fmaxf(m, abuf[eidx[begin + k]]);
    #pragma unroll
    for (int off = 32; off; off >>= 1) m = fmaxf(m, __shfl_xor(m, off));

    float s = 0.f;
    for (int k = lane; k < deg; k += 64) s += expf(abuf[eidx[begin + k]] - m);
    #pragma unroll
    for (int off = 32; off; off >>= 1) s += __shfl_xor(s, off);

    float inv_s = 1.0f / fmaxf(s, 1e-9f);

    float acc = 0.f;
    for (int k = 0; k < deg; ++k) {
        int eid = eidx[begin + k];
        float alpha = expf(abuf[eid] - m) * inv_s;
        acc = fmaf(alpha, z_h[(size_t)src[eid] * DIM + lane], acc);
    }
    hout[(size_t)wid * DIM + lane] = fmaxf(acc, 0.f);
}

extern "C" void kernel_launch(void* const* d_in, const int* in_sizes, int n_in,
                              void* d_out, int out_size, void* d_ws, size_t ws_size,
                              hipStream_t stream)
{
    const float* h   = (const float*)d_in[0];
    const float* e   = (const float*)d_in[1];
    const int*   src = (const int*)d_in[2];
    const int*   dst = (const int*)d_in[3];
    const float* Wh1 = (const float*)d_in[4];
    const float* Wh2 = (const float*)d_in[5];
    const float* We1 = (const float*)d_in[6];
    const float* We2 = (const float*)d_in[7];
    const float* Wp1 = (const float*)d_in[8];
    const float* bp1 = (const float*)d_in[9];
    const float* Wp2 = (const float*)d_in[10];
    const float* bp2 = (const float*)d_in[11];
    const float* Wa  = (const float*)d_in[12];

    const int N = in_sizes[0] / DIM;
    const int E = in_sizes[1] / DIM;

    float* ws   = (float*)d_ws;
    float* z_h  = ws;  ws += (size_t)N * DIM;
    float* u_s  = ws;  ws += (size_t)N * DIM;
    float* u_d  = ws;  ws += (size_t)N * DIM;
    float* as_  = ws;  ws += N;
    float* ad_  = ws;  ws += N;
    float* abuf = ws;  ws += E;
    int* cnt    = (int*)ws;  ws += N;
    int* ofs    = (int*)ws;  ws += N;
    int* cursor = (int*)ws;  ws += N;
    int* eidx   = (int*)ws;  ws += E;
    unsigned short* whi = (unsigned short*)ws;  ws += 16384 / 2;   // 16384 bf16
    unsigned short* wlo = (unsigned short*)ws;  ws += 16384 / 2;

    float* hout  = (float*)d_out;
    float* eproj = hout + (size_t)N * DIM;

    hipMemsetAsync(cnt, 0, (size_t)N * sizeof(int), stream);

    k_prep<<<64, 256, 0, stream>>>(We1, We2, Wp1, Wp2, whi, wlo);

    node_kernel<<<(N + TPB - 1) / TPB, TPB, 0, stream>>>(
        h, Wh1, Wh2, Wp1, Wa, z_h, u_s, u_d, as_, ad_, N);

    edge_mfma<<<(E + BM - 1) / BM, 256, 0, stream>>>(
        e, src, dst, u_s, u_d, as_, ad_, whi, wlo, Wa, bp1, bp2,
        eproj, abuf, E);

    k_hist<<<(E + 255) / 256, 256, 0, stream>>>(dst, cnt, E);
    k_scan<<<1, SCAN_T, 0, stream>>>(cnt, ofs, cursor, N);
    k_fill<<<(E + 255) / 256, 256, 0, stream>>>(dst, cursor, eidx, E);

    k_aggregate<<<((N * 64) + 255) / 256, 256, 0, stream>>>(
        abuf, eidx, ofs, cnt, src, z_h, hout, N);
}

// Round 4
// 387.658 us; speedup vs baseline: 3.5451x; 1.7116x over previous
//
#include <hip/hip_runtime.h>
#include <hip/hip_bf16.h>

#define DIM 64
#define BM 128

typedef __attribute__((ext_vector_type(8))) short bf16x8;
typedef __attribute__((ext_vector_type(4))) float f32x4;

// HW bf16 conversion (v_cvt_pk_bf16_f32) — RNE, ~3 VALU/elem vs ~10 for bit-twiddled
__device__ __forceinline__ short f2bf_hw(float x) {
    __hip_bfloat16 b = __float2bfloat16(x);
    return (short)reinterpret_cast<unsigned short&>(b);
}
__device__ __forceinline__ float bf2f_hw(short s) {
    unsigned u = ((unsigned)(unsigned short)s) << 16;
    return __uint_as_float(u);
}
__device__ __forceinline__ void split8(float4 a, float4 b, bf16x8& hi, bf16x8& lo) {
    float v[8] = {a.x, a.y, a.z, a.w, b.x, b.y, b.z, b.w};
    #pragma unroll
    for (int i = 0; i < 8; ++i) {
        short h = f2bf_hw(v[i]);
        hi[i] = h;
        lo[i] = f2bf_hw(v[i] - bf2f_hw(h));
    }
}
// XOR-swizzle (T2): byte address within act tile; row stride 256B
__device__ __forceinline__ int swz(int row, int colbyte) {
    return row * 256 + (colbyte ^ ((row & 7) << 4));
}

// ---- weight prep: 8 layers (0..3 edge: We1,We2,Wp1top,Wp2; 4..7 node:
// Wh1,Wh2,Wp1mid,Wp1bot), split hi/lo bf16, MFMA B-fragment order:
// w[layer][kt][nt][lane][e], k = kt*32+(lane>>4)*8+e, n = nt*16+(lane&15)
__global__ __launch_bounds__(256) void k_prep(
    const float* __restrict__ We1, const float* __restrict__ We2,
    const float* __restrict__ Wp1, const float* __restrict__ Wp2,
    const float* __restrict__ Wh1, const float* __restrict__ Wh2,
    unsigned short* __restrict__ whi, unsigned short* __restrict__ wlo)
{
    int t = blockIdx.x * 256 + threadIdx.x;     // 0..32767
    int e_ = t & 7, lane = (t >> 3) & 63, frag = (t >> 9) & 7, layer = t >> 12;
    int kt = frag >> 2, nt = frag & 3;
    int k = kt * 32 + ((lane >> 4) * 8) + e_;
    int n = nt * 16 + (lane & 15);
    const float* W;
    switch (layer) {
        case 0: W = We1; break;
        case 1: W = We2; break;
        case 2: W = Wp1; break;
        case 3: W = Wp2; break;
        case 4: W = Wh1; break;
        case 5: W = Wh2; break;
        case 6: W = Wp1 + 64 * 64; break;
        default: W = Wp1 + 128 * 64; break;
    }
    float w = W[k * 64 + n];
    short h = f2bf_hw(w);
    whi[t] = (unsigned short)h;
    wlo[t] = (unsigned short)f2bf_hw(w - bf2f_hw(h));
}

// ---- node pipeline via MFMA: 128 nodes/block, 4 waves x 32 wave-private rows
__global__ __launch_bounds__(256) void node_mfma(
    const float* __restrict__ h,
    const unsigned short* __restrict__ whi, const unsigned short* __restrict__ wlo,
    const float* __restrict__ Wa,
    float* __restrict__ z_h, float* __restrict__ u_s, float* __restrict__ u_d,
    float* __restrict__ as_, float* __restrict__ ad_, int N)
{
    __shared__ float act[BM * 64];
    char* lds = (char*)act;
    const int lane  = threadIdx.x & 63;
    const int wave  = threadIdx.x >> 6;
    const int wrow0 = wave * 32;
    const long node0 = (long)blockIdx.x * BM;
    const int g   = lane >> 4;
    const int c15 = lane & 15;

    float was[4], wad[4];
    #pragma unroll
    for (int nt = 0; nt < 4; ++nt) {
        was[nt] = Wa[64  + nt * 16 + c15];
        wad[nt] = Wa[128 + nt * 16 + c15];
    }

    f32x4 acc[2][4];
    auto zacc = [&]() {
        #pragma unroll
        for (int mt = 0; mt < 2; ++mt)
            #pragma unroll
            for (int nt = 0; nt < 4; ++nt)
                #pragma unroll
                for (int rr = 0; rr < 4; ++rr) acc[mt][nt][rr] = 0.f;
    };

    auto mfma_layer = [&](int layer) {
        #pragma unroll
        for (int kt = 0; kt < 2; ++kt) {
            bf16x8 ah[2], al[2];
            #pragma unroll
            for (int mt = 0; mt < 2; ++mt) {
                float4 a0, a1;
                if (layer == 4) {           // A from global h
                    long nr = node0 + wrow0 + mt * 16 + c15; if (nr >= N) nr = N - 1;
                    const float* p = h + nr * 64 + kt * 32 + g * 8;
                    a0 = *(const float4*)p;
                    a1 = *(const float4*)(p + 4);
                } else {
                    int row = wrow0 + mt * 16 + c15;
                    int cb  = kt * 128 + g * 32;
                    a0 = *(const float4*)(lds + swz(row, cb));
                    a1 = *(const float4*)(lds + swz(row, cb + 16));
                }
                split8(a0, a1, ah[mt], al[mt]);
            }
            #pragma unroll
            for (int nt = 0; nt < 4; ++nt) {
                int fo = ((layer * 8 + kt * 4 + nt) * 64 + lane) * 8;
                bf16x8 bh = *(const bf16x8*)(whi + fo);
                bf16x8 bl = *(const bf16x8*)(wlo + fo);
                #pragma unroll
                for (int mt = 0; mt < 2; ++mt) {
                    acc[mt][nt] = __builtin_amdgcn_mfma_f32_16x16x32_bf16(ah[mt], bh, acc[mt][nt], 0, 0, 0);
                    acc[mt][nt] = __builtin_amdgcn_mfma_f32_16x16x32_bf16(ah[mt], bl, acc[mt][nt], 0, 0, 0);
                    acc[mt][nt] = __builtin_amdgcn_mfma_f32_16x16x32_bf16(al[mt], bh, acc[mt][nt], 0, 0, 0);
                }
            }
        }
    };

    auto writeback = [&](bool relu) {
        #pragma unroll
        for (int mt = 0; mt < 2; ++mt)
            #pragma unroll
            for (int nt = 0; nt < 4; ++nt)
                #pragma unroll
                for (int rr = 0; rr < 4; ++rr) {
                    int row  = wrow0 + mt * 16 + g * 4 + rr;
                    int colb = (nt * 16 + c15) * 4;
                    float v = acc[mt][nt][rr];
                    if (relu) v = fmaxf(v, 0.f);
                    *(float*)(lds + swz(row, colb)) = v;
                }
    };

    auto store_global = [&](float* __restrict__ out) {
        #pragma unroll
        for (int mt = 0; mt < 2; ++mt)
            #pragma unroll
            for (int nt = 0; nt < 4; ++nt)
                #pragma unroll
                for (int rr = 0; rr < 4; ++rr) {
                    long nr = node0 + wrow0 + mt * 16 + g * 4 + rr; if (nr >= N) nr = N - 1;
                    out[nr * 64 + nt * 16 + c15] = acc[mt][nt][rr];
                }
    };

    // L1: t1 = relu(h @ Wh1)
    zacc(); mfma_layer(4); writeback(true);
    // L2: z_h = t1 @ Wh2
    zacc(); mfma_layer(5);

    // as = z_h . Wa[64:128], ad = z_h . Wa[128:192]
    #pragma unroll
    for (int mt = 0; mt < 2; ++mt) {
        float ps[4], pd[4];
        #pragma unroll
        for (int rr = 0; rr < 4; ++rr) {
            ps[rr] = acc[mt][0][rr] * was[0] + acc[mt][1][rr] * was[1]
                   + acc[mt][2][rr] * was[2] + acc[mt][3][rr] * was[3];
            pd[rr] = acc[mt][0][rr] * wad[0] + acc[mt][1][rr] * wad[1]
                   + acc[mt][2][rr] * wad[2] + acc[mt][3][rr] * wad[3];
        }
        #pragma unroll
        for (int off = 1; off < 16; off <<= 1)
            #pragma unroll
            for (int rr = 0; rr < 4; ++rr) {
                ps[rr] += __shfl_xor(ps[rr], off);
                pd[rr] += __shfl_xor(pd[rr], off);
            }
        if (c15 == 0) {
            #pragma unroll
            for (int rr = 0; rr < 4; ++rr) {
                long nr = node0 + wrow0 + mt * 16 + g * 4 + rr; if (nr >= N) nr = N - 1;
                as_[nr] = ps[rr];
                ad_[nr] = pd[rr];
            }
        }
    }
    store_global(z_h);
    writeback(false);   // z_h -> LDS for L3/L4

    // L3: u_s = z_h @ Wp1[64:128]
    zacc(); mfma_layer(6); store_global(u_s);
    // L4: u_d = z_h @ Wp1[128:192]  (LDS still holds z_h — L3 didn't write LDS)
    zacc(); mfma_layer(7); store_global(u_d);
}

// ---- edge pipeline: split-bf16 MFMA chain, wave-private rows, no barriers
__global__ __launch_bounds__(256) void edge_mfma(
    const float* __restrict__ e, const int* __restrict__ src, const int* __restrict__ dst,
    const float* __restrict__ u_s, const float* __restrict__ u_d,
    const float* __restrict__ as_, const float* __restrict__ ad_,
    const unsigned short* __restrict__ whi, const unsigned short* __restrict__ wlo,
    const float* __restrict__ Wa, const float* __restrict__ bp1, const float* __restrict__ bp2,
    float* __restrict__ eproj, float* __restrict__ abuf, int E)
{
    __shared__ float act[BM * 64];
    char* lds = (char*)act;
    const int lane  = threadIdx.x & 63;
    const int wave  = threadIdx.x >> 6;
    const int wrow0 = wave * 32;
    const long edge0 = (long)blockIdx.x * BM;
    const int g   = lane >> 4;
    const int c15 = lane & 15;

    int sn[2][4], dn[2][4];
    #pragma unroll
    for (int mt = 0; mt < 2; ++mt)
        #pragma unroll
        for (int rr = 0; rr < 4; ++rr) {
            long er = edge0 + wrow0 + mt * 16 + g * 4 + rr; if (er >= E) er = E - 1;
            sn[mt][rr] = src[er]; dn[mt][rr] = dst[er];
        }

    float waf[4], b1f[4], b2f[4];
    #pragma unroll
    for (int nt = 0; nt < 4; ++nt) {
        waf[nt] = Wa[nt * 16 + c15];
        b1f[nt] = bp1[nt * 16 + c15];
        b2f[nt] = bp2[nt * 16 + c15];
    }

    float uv[2][4][4], asv[2][4];
    #pragma unroll
    for (int mt = 0; mt < 2; ++mt)
        #pragma unroll
        for (int rr = 0; rr < 4; ++rr) {
            const float* us = u_s + (size_t)sn[mt][rr] * DIM;
            const float* ud = u_d + (size_t)dn[mt][rr] * DIM;
            #pragma unroll
            for (int nt = 0; nt < 4; ++nt)
                uv[mt][nt][rr] = us[nt * 16 + c15] + ud[nt * 16 + c15] + b1f[nt];
            asv[mt][rr] = as_[sn[mt][rr]] + ad_[dn[mt][rr]];
        }

    f32x4 acc[2][4];
    auto zacc = [&]() {
        #pragma unroll
        for (int mt = 0; mt < 2; ++mt)
            #pragma unroll
            for (int nt = 0; nt < 4; ++nt)
                #pragma unroll
                for (int rr = 0; rr < 4; ++rr) acc[mt][nt][rr] = 0.f;
    };

    auto mfma_layer = [&](int layer) {
        #pragma unroll
        for (int kt = 0; kt < 2; ++kt) {
            bf16x8 ah[2], al[2];
            #pragma unroll
            for (int mt = 0; mt < 2; ++mt) {
                float4 a0, a1;
                if (layer == 0) {
                    long er = edge0 + wrow0 + mt * 16 + c15; if (er >= E) er = E - 1;
                    const float* p = e + er * 64 + kt * 32 + g * 8;
                    a0 = *(const float4*)p;
                    a1 = *(const float4*)(p + 4);
                } else {
                    int row = wrow0 + mt * 16 + c15;
                    int cb  = kt * 128 + g * 32;
                    a0 = *(const float4*)(lds + swz(row, cb));
                    a1 = *(const float4*)(lds + swz(row, cb + 16));
                }
                split8(a0, a1, ah[mt], al[mt]);
            }
            #pragma unroll
            for (int nt = 0; nt < 4; ++nt) {
                int fo = ((layer * 8 + kt * 4 + nt) * 64 + lane) * 8;
                bf16x8 bh = *(const bf16x8*)(whi + fo);
                bf16x8 bl = *(const bf16x8*)(wlo + fo);
                #pragma unroll
                for (int mt = 0; mt < 2; ++mt) {
                    acc[mt][nt] = __builtin_amdgcn_mfma_f32_16x16x32_bf16(ah[mt], bh, acc[mt][nt], 0, 0, 0);
                    acc[mt][nt] = __builtin_amdgcn_mfma_f32_16x16x32_bf16(ah[mt], bl, acc[mt][nt], 0, 0, 0);
                    acc[mt][nt] = __builtin_amdgcn_mfma_f32_16x16x32_bf16(al[mt], bh, acc[mt][nt], 0, 0, 0);
                }
            }
        }
    };

    auto writeback = [&](bool relu) {
        #pragma unroll
        for (int mt = 0; mt < 2; ++mt)
            #pragma unroll
            for (int nt = 0; nt < 4; ++nt)
                #pragma unroll
                for (int rr = 0; rr < 4; ++rr) {
                    int row  = wrow0 + mt * 16 + g * 4 + rr;
                    int colb = (nt * 16 + c15) * 4;
                    float v = acc[mt][nt][rr];
                    if (relu) v = fmaxf(v, 0.f);
                    *(float*)(lds + swz(row, colb)) = v;
                }
    };

    // L1: t1 = relu(e @ We1)
    zacc(); mfma_layer(0); writeback(true);
    // L2: z_e = t1 @ We2
    zacc(); mfma_layer(1);

    // attention: ae = z_e . Wa[0:64]; a = relu(ae + as[src] + ad[dst])
    #pragma unroll
    for (int mt = 0; mt < 2; ++mt) {
        float part[4];
        #pragma unroll
        for (int rr = 0; rr < 4; ++rr)
            part[rr] = acc[mt][0][rr] * waf[0] + acc[mt][1][rr] * waf[1]
                     + acc[mt][2][rr] * waf[2] + acc[mt][3][rr] * waf[3];
        #pragma unroll
        for (int off = 1; off < 16; off <<= 1)
            #pragma unroll
            for (int rr = 0; rr < 4; ++rr) part[rr] += __shfl_xor(part[rr], off);
        if (c15 == 0) {
            #pragma unroll
            for (int rr = 0; rr < 4; ++rr) {
                long er = edge0 + wrow0 + mt * 16 + g * 4 + rr; if (er >= E) er = E - 1;
                abuf[er] = fmaxf(part[rr] + asv[mt][rr], 0.f);
            }
        }
    }
    writeback(false);

    // L3: t2 = relu(z_e @ Wp1top + u_s[src] + u_d[dst] + bp1)
    zacc(); mfma_layer(2);
    #pragma unroll
    for (int mt = 0; mt < 2; ++mt)
        #pragma unroll
        for (int nt = 0; nt < 4; ++nt)
            #pragma unroll
            for (int rr = 0; rr < 4; ++rr)
                acc[mt][nt][rr] += uv[mt][nt][rr];
    writeback(true);

    // L4: eproj = relu(t2 @ Wp2 + bp2)
    zacc(); mfma_layer(3);
    #pragma unroll
    for (int mt = 0; mt < 2; ++mt)
        #pragma unroll
        for (int nt = 0; nt < 4; ++nt)
            #pragma unroll
            for (int rr = 0; rr < 4; ++rr) {
                long er = edge0 + wrow0 + mt * 16 + g * 4 + rr; if (er >= E) er = E - 1;
                eproj[er * 64 + nt * 16 + c15] = fmaxf(acc[mt][nt][rr] + b2f[nt], 0.f);
            }
}

// ---- CSR build ----
__global__ __launch_bounds__(256) void k_hist(
    const int* __restrict__ dst, int* __restrict__ cnt, int E)
{
    int i = blockIdx.x * 256 + threadIdx.x;
    if (i < E) atomicAdd(&cnt[dst[i]], 1);
}

// multi-block exclusive scan: scan1 (per-block) -> scan2 (block sums) -> scan3 (add)
__global__ __launch_bounds__(256) void k_scan1(
    const int* __restrict__ cnt, int* __restrict__ ofs, int* __restrict__ bsum, int N)
{
    __shared__ int sm[256];
    int t = threadIdx.x, i = blockIdx.x * 256 + t;
    int v = (i < N) ? cnt[i] : 0;
    sm[t] = v;
    __syncthreads();
    #pragma unroll
    for (int off = 1; off < 256; off <<= 1) {
        int tmp = (t >= off) ? sm[t - off] : 0;
        __syncthreads();
        sm[t] += tmp;
        __syncthreads();
    }
    if (i < N) ofs[i] = sm[t] - v;
    if (t == 255) bsum[blockIdx.x] = sm[255];
}

__global__ __launch_bounds__(256) void k_scan2(int* __restrict__ bsum, int NB)
{
    __shared__ int sm[256];
    int t = threadIdx.x;
    int v = (t < NB) ? bsum[t] : 0;
    sm[t] = v;
    __syncthreads();
    #pragma unroll
    for (int off = 1; off < 256; off <<= 1) {
        int tmp = (t >= off) ? sm[t - off] : 0;
        __syncthreads();
        sm[t] += tmp;
        __syncthreads();
    }
    if (t < NB) bsum[t] = sm[t] - v;   // exclusive
}

__global__ __launch_bounds__(256) void k_scan3(
    int* __restrict__ ofs, int* __restrict__ cursor,
    const int* __restrict__ bsum, int N)
{
    int i = blockIdx.x * 256 + threadIdx.x;
    if (i < N) {
        int o = ofs[i] + bsum[blockIdx.x];
        ofs[i] = o;
        cursor[i] = o;
    }
}

__global__ __launch_bounds__(256) void k_fill(
    const int* __restrict__ dst, int* __restrict__ cursor, int* __restrict__ eidx, int E)
{
    int i = blockIdx.x * 256 + threadIdx.x;
    if (i < E) {
        int p = atomicAdd(&cursor[dst[i]], 1);
        eidx[p] = i;
    }
}

// ---- fused segment softmax + weighted gather: 1 wave/node, 4 edges in flight,
// 16 lanes x float4 per edge row
__global__ __launch_bounds__(256) void k_aggregate(
    const float* __restrict__ abuf, const int* __restrict__ eidx,
    const int* __restrict__ ofs, const int* __restrict__ cnt,
    const int* __restrict__ src, const float* __restrict__ z_h,
    float* __restrict__ hout, int N)
{
    int wid  = (blockIdx.x * 256 + threadIdx.x) >> 6;
    int lane = threadIdx.x & 63;
    if (wid >= N) return;
    int grp = lane >> 4, c15 = lane & 15;

    int begin = ofs[wid];
    int deg   = cnt[wid];

    // segment max (scores >= 0; init 0 matches reference's zero-degree semantics)
    float m = 0.f;
    for (int k = lane; k < deg; k += 64) m = fmaxf(m, abuf[eidx[begin + k]]);
    #pragma unroll
    for (int off = 32; off; off >>= 1) m = fmaxf(m, __shfl_xor(m, off));

    float s = 0.f;
    for (int k = lane; k < deg; k += 64) s += expf(abuf[eidx[begin + k]] - m);
    #pragma unroll
    for (int off = 32; off; off >>= 1) s += __shfl_xor(s, off);

    float inv_s = 1.0f / fmaxf(s, 1e-9f);

    float4 acc = make_float4(0.f, 0.f, 0.f, 0.f);
    for (int k = grp; k < deg; k += 4) {
        int eid = eidx[begin + k];
        float alpha = expf(abuf[eid] - m) * inv_s;
        const float4 v = *(const float4*)(z_h + (size_t)src[eid] * DIM + c15 * 4);
        acc.x = fmaf(alpha, v.x, acc.x);
        acc.y = fmaf(alpha, v.y, acc.y);
        acc.z = fmaf(alpha, v.z, acc.z);
        acc.w = fmaf(alpha, v.w, acc.w);
    }
    // combine the 4 groups (lanes l, l+16, l+32, l+48 hold same features)
    #pragma unroll
    for (int off = 16; off <= 32; off <<= 1) {
        acc.x += __shfl_xor(acc.x, off);
        acc.y += __shfl_xor(acc.y, off);
        acc.z += __shfl_xor(acc.z, off);
        acc.w += __shfl_xor(acc.w, off);
    }
    if (grp == 0) {
        float4 r = make_float4(fmaxf(acc.x, 0.f), fmaxf(acc.y, 0.f),
                               fmaxf(acc.z, 0.f), fmaxf(acc.w, 0.f));
        *(float4*)(hout + (size_t)wid * DIM + c15 * 4) = r;
    }
}

extern "C" void kernel_launch(void* const* d_in, const int* in_sizes, int n_in,
                              void* d_out, int out_size, void* d_ws, size_t ws_size,
                              hipStream_t stream)
{
    const float* h   = (const float*)d_in[0];
    const float* e   = (const float*)d_in[1];
    const int*   src = (const int*)d_in[2];
    const int*   dst = (const int*)d_in[3];
    const float* Wh1 = (const float*)d_in[4];
    const float* Wh2 = (const float*)d_in[5];
    const float* We1 = (const float*)d_in[6];
    const float* We2 = (const float*)d_in[7];
    const float* Wp1 = (const float*)d_in[8];
    const float* bp1 = (const float*)d_in[9];
    const float* Wp2 = (const float*)d_in[10];
    const float* bp2 = (const float*)d_in[11];
    const float* Wa  = (const float*)d_in[12];

    const int N = in_sizes[0] / DIM;
    const int E = in_sizes[1] / DIM;

    float* ws   = (float*)d_ws;
    float* z_h  = ws;  ws += (size_t)N * DIM;
    float* u_s  = ws;  ws += (size_t)N * DIM;
    float* u_d  = ws;  ws += (size_t)N * DIM;
    float* as_  = ws;  ws += N;
    float* ad_  = ws;  ws += N;
    float* abuf = ws;  ws += E;
    int* cnt    = (int*)ws;  ws += N;
    int* ofs    = (int*)ws;  ws += N;
    int* cursor = (int*)ws;  ws += N;
    int* eidx   = (int*)ws;  ws += E;
    int* bsum   = (int*)ws;  ws += 256;
    unsigned short* whi = (unsigned short*)ws;  ws += 32768 / 2;   // 8 layers x 4096 bf16
    unsigned short* wlo = (unsigned short*)ws;  ws += 32768 / 2;

    float* hout  = (float*)d_out;
    float* eproj = hout + (size_t)N * DIM;

    const int NB = (N + 255) / 256;   // scan blocks (N=50000 -> 196 <= 256)

    hipMemsetAsync(cnt, 0, (size_t)N * sizeof(int), stream);

    k_prep<<<128, 256, 0, stream>>>(We1, We2, Wp1, Wp2, Wh1, Wh2, whi, wlo);

    node_mfma<<<(N + BM - 1) / BM, 256, 0, stream>>>(
        h, whi, wlo, Wa, z_h, u_s, u_d, as_, ad_, N);

    edge_mfma<<<(E + BM - 1) / BM, 256, 0, stream>>>(
        e, src, dst, u_s, u_d, as_, ad_, whi, wlo, Wa, bp1, bp2,
        eproj, abuf, E);

    k_hist<<<(E + 255) / 256, 256, 0, stream>>>(dst, cnt, E);
    k_scan1<<<NB, 256, 0, stream>>>(cnt, ofs, bsum, N);
    k_scan2<<<1, 256, 0, stream>>>(bsum, NB);
    k_scan3<<<NB, 256, 0, stream>>>(ofs, cursor, bsum, N);
    k_fill<<<(E + 255) / 256, 256, 0, stream>>>(dst, cursor, eidx, E);

    k_aggregate<<<((N * 64) + 255) / 256, 256, 0, stream>>>(
        abuf, eidx, ofs, cnt, src, z_h, hout, N);
}

// Round 6
// 380.461 us; speedup vs baseline: 3.6122x; 1.0189x over previous
//
#include <hip/hip_runtime.h>
#include <hip/hip_bf16.h>

#define DIM 64
#define BM 128

typedef __attribute__((ext_vector_type(8))) short bf16x8;
typedef __attribute__((ext_vector_type(4))) float f32x4;

__device__ __forceinline__ short f2bf_hw(float x) {
    __hip_bfloat16 b = __float2bfloat16(x);
    return (short)reinterpret_cast<unsigned short&>(b);
}
__device__ __forceinline__ float bf2f_hw(short s) {
    unsigned u = ((unsigned)(unsigned short)s) << 16;
    return __uint_as_float(u);
}
__device__ __forceinline__ void split8(float4 a, float4 b, bf16x8& hi, bf16x8& lo) {
    float v[8] = {a.x, a.y, a.z, a.w, b.x, b.y, b.z, b.w};
    #pragma unroll
    for (int i = 0; i < 8; ++i) {
        short h = f2bf_hw(v[i]);
        hi[i] = h;
        lo[i] = f2bf_hw(v[i] - bf2f_hw(h));
    }
}
// XOR-swizzle (T2): byte address within act tile; row stride 256B
__device__ __forceinline__ int swz(int row, int colbyte) {
    return row * 256 + (colbyte ^ ((row & 7) << 4));
}

// ---- weight prep: 8 layers (0..3 edge: We1,We2,Wp1top,Wp2; 4..7 node:
// Wh1,Wh2,Wp1mid,Wp1bot), split hi/lo bf16, MFMA B-fragment order:
// w[layer][kt][nt][lane][e], k = kt*32+(lane>>4)*8+e, n = nt*16+(lane&15)
__global__ __launch_bounds__(256) void k_prep(
    const float* __restrict__ We1, const float* __restrict__ We2,
    const float* __restrict__ Wp1, const float* __restrict__ Wp2,
    const float* __restrict__ Wh1, const float* __restrict__ Wh2,
    unsigned short* __restrict__ whi, unsigned short* __restrict__ wlo)
{
    int t = blockIdx.x * 256 + threadIdx.x;     // 0..32767
    int e_ = t & 7, lane = (t >> 3) & 63, frag = (t >> 9) & 7, layer = t >> 12;
    int kt = frag >> 2, nt = frag & 3;
    int k = kt * 32 + ((lane >> 4) * 8) + e_;
    int n = nt * 16 + (lane & 15);
    const float* W;
    switch (layer) {
        case 0: W = We1; break;
        case 1: W = We2; break;
        case 2: W = Wp1; break;
        case 3: W = Wp2; break;
        case 4: W = Wh1; break;
        case 5: W = Wh2; break;
        case 6: W = Wp1 + 64 * 64; break;
        default: W = Wp1 + 128 * 64; break;
    }
    float w = W[k * 64 + n];
    short h = f2bf_hw(w);
    whi[t] = (unsigned short)h;
    wlo[t] = (unsigned short)f2bf_hw(w - bf2f_hw(h));
}

// ---- node pipeline via MFMA: 128 nodes/block, 4 waves x 32 wave-private rows
__global__ __launch_bounds__(256) void node_mfma(
    const float* __restrict__ h,
    const unsigned short* __restrict__ whi, const unsigned short* __restrict__ wlo,
    const float* __restrict__ Wa,
    float* __restrict__ z_h, float* __restrict__ u_s, float* __restrict__ u_d,
    float* __restrict__ as_, float* __restrict__ ad_, int N)
{
    __shared__ float act[BM * 64];
    char* lds = (char*)act;
    const int lane  = threadIdx.x & 63;
    const int wave  = threadIdx.x >> 6;
    const int wrow0 = wave * 32;
    const long node0 = (long)blockIdx.x * BM;
    const int g   = lane >> 4;
    const int c15 = lane & 15;

    float was[4], wad[4];
    #pragma unroll
    for (int nt = 0; nt < 4; ++nt) {
        was[nt] = Wa[64  + nt * 16 + c15];
        wad[nt] = Wa[128 + nt * 16 + c15];
    }

    f32x4 acc[2][4];
    auto zacc = [&]() {
        #pragma unroll
        for (int mt = 0; mt < 2; ++mt)
            #pragma unroll
            for (int nt = 0; nt < 4; ++nt)
                #pragma unroll
                for (int rr = 0; rr < 4; ++rr) acc[mt][nt][rr] = 0.f;
    };

    auto mfma_layer = [&](int layer) {
        #pragma unroll
        for (int kt = 0; kt < 2; ++kt) {
            bf16x8 ah[2], al[2];
            #pragma unroll
            for (int mt = 0; mt < 2; ++mt) {
                float4 a0, a1;
                if (layer == 4) {           // A from global h
                    long nr = node0 + wrow0 + mt * 16 + c15; if (nr >= N) nr = N - 1;
                    const float* p = h + nr * 64 + kt * 32 + g * 8;
                    a0 = *(const float4*)p;
                    a1 = *(const float4*)(p + 4);
                } else {
                    int row = wrow0 + mt * 16 + c15;
                    int cb  = kt * 128 + g * 32;
                    a0 = *(const float4*)(lds + swz(row, cb));
                    a1 = *(const float4*)(lds + swz(row, cb + 16));
                }
                split8(a0, a1, ah[mt], al[mt]);
            }
            #pragma unroll
            for (int nt = 0; nt < 4; ++nt) {
                int fo = ((layer * 8 + kt * 4 + nt) * 64 + lane) * 8;
                bf16x8 bh = *(const bf16x8*)(whi + fo);
                bf16x8 bl = *(const bf16x8*)(wlo + fo);
                #pragma unroll
                for (int mt = 0; mt < 2; ++mt) {
                    acc[mt][nt] = __builtin_amdgcn_mfma_f32_16x16x32_bf16(ah[mt], bh, acc[mt][nt], 0, 0, 0);
                    acc[mt][nt] = __builtin_amdgcn_mfma_f32_16x16x32_bf16(ah[mt], bl, acc[mt][nt], 0, 0, 0);
                    acc[mt][nt] = __builtin_amdgcn_mfma_f32_16x16x32_bf16(al[mt], bh, acc[mt][nt], 0, 0, 0);
                }
            }
        }
    };

    auto writeback = [&](bool relu) {
        #pragma unroll
        for (int mt = 0; mt < 2; ++mt)
            #pragma unroll
            for (int nt = 0; nt < 4; ++nt)
                #pragma unroll
                for (int rr = 0; rr < 4; ++rr) {
                    int row  = wrow0 + mt * 16 + g * 4 + rr;
                    int colb = (nt * 16 + c15) * 4;
                    float v = acc[mt][nt][rr];
                    if (relu) v = fmaxf(v, 0.f);
                    *(float*)(lds + swz(row, colb)) = v;
                }
    };

    auto store_global = [&](float* __restrict__ out) {
        #pragma unroll
        for (int mt = 0; mt < 2; ++mt)
            #pragma unroll
            for (int nt = 0; nt < 4; ++nt)
                #pragma unroll
                for (int rr = 0; rr < 4; ++rr) {
                    long nr = node0 + wrow0 + mt * 16 + g * 4 + rr; if (nr >= N) nr = N - 1;
                    out[nr * 64 + nt * 16 + c15] = acc[mt][nt][rr];
                }
    };

    // L1: t1 = relu(h @ Wh1)
    zacc(); mfma_layer(4); writeback(true);
    // L2: z_h = t1 @ Wh2
    zacc(); mfma_layer(5);

    // as = z_h . Wa[64:128], ad = z_h . Wa[128:192]
    #pragma unroll
    for (int mt = 0; mt < 2; ++mt) {
        float ps[4], pd[4];
        #pragma unroll
        for (int rr = 0; rr < 4; ++rr) {
            ps[rr] = acc[mt][0][rr] * was[0] + acc[mt][1][rr] * was[1]
                   + acc[mt][2][rr] * was[2] + acc[mt][3][rr] * was[3];
            pd[rr] = acc[mt][0][rr] * wad[0] + acc[mt][1][rr] * wad[1]
                   + acc[mt][2][rr] * wad[2] + acc[mt][3][rr] * wad[3];
        }
        #pragma unroll
        for (int off = 1; off < 16; off <<= 1)
            #pragma unroll
            for (int rr = 0; rr < 4; ++rr) {
                ps[rr] += __shfl_xor(ps[rr], off);
                pd[rr] += __shfl_xor(pd[rr], off);
            }
        if (c15 == 0) {
            #pragma unroll
            for (int rr = 0; rr < 4; ++rr) {
                long nr = node0 + wrow0 + mt * 16 + g * 4 + rr; if (nr >= N) nr = N - 1;
                as_[nr] = ps[rr];
                ad_[nr] = pd[rr];
            }
        }
    }
    store_global(z_h);
    writeback(false);   // z_h -> LDS for L3/L4

    // L3: u_s = z_h @ Wp1[64:128]
    zacc(); mfma_layer(6); store_global(u_s);
    // L4: u_d = z_h @ Wp1[128:192]  (LDS still holds z_h)
    zacc(); mfma_layer(7); store_global(u_d);
}

// ---- edge pipeline: split-bf16 MFMA chain, wave-private rows, no barriers.
// Also performs the CSR fill (cursor/eidx) — cursor must be ready at launch.
__global__ __launch_bounds__(256) void edge_mfma(
    const float* __restrict__ e, const int* __restrict__ src, const int* __restrict__ dst,
    const float* __restrict__ u_s, const float* __restrict__ u_d,
    const float* __restrict__ as_, const float* __restrict__ ad_,
    const unsigned short* __restrict__ whi, const unsigned short* __restrict__ wlo,
    const float* __restrict__ Wa, const float* __restrict__ bp1, const float* __restrict__ bp2,
    float* __restrict__ eproj, float* __restrict__ abuf,
    int* __restrict__ cursor, int* __restrict__ eidx, int E)
{
    __shared__ float act[BM * 64];
    char* lds = (char*)act;
    const int lane  = threadIdx.x & 63;
    const int wave  = threadIdx.x >> 6;
    const int wrow0 = wave * 32;
    const long edge0 = (long)blockIdx.x * BM;
    const int g   = lane >> 4;
    const int c15 = lane & 15;

    int sn[2][4], dn[2][4];
    #pragma unroll
    for (int mt = 0; mt < 2; ++mt)
        #pragma unroll
        for (int rr = 0; rr < 4; ++rr) {
            long er0 = edge0 + wrow0 + mt * 16 + g * 4 + rr;
            long er = er0 >= E ? E - 1 : er0;
            sn[mt][rr] = src[er]; dn[mt][rr] = dst[er];
            // fused CSR fill (one lane per row)
            if (c15 == 0 && er0 < E) {
                int p = atomicAdd(&cursor[dn[mt][rr]], 1);
                eidx[p] = (int)er0;
            }
        }

    float waf[4], b1f[4], b2f[4];
    #pragma unroll
    for (int nt = 0; nt < 4; ++nt) {
        waf[nt] = Wa[nt * 16 + c15];
        b1f[nt] = bp1[nt * 16 + c15];
        b2f[nt] = bp2[nt * 16 + c15];
    }

    float asv[2][4];
    #pragma unroll
    for (int mt = 0; mt < 2; ++mt)
        #pragma unroll
        for (int rr = 0; rr < 4; ++rr)
            asv[mt][rr] = as_[sn[mt][rr]] + ad_[dn[mt][rr]];

    f32x4 acc[2][4];
    auto zacc = [&]() {
        #pragma unroll
        for (int mt = 0; mt < 2; ++mt)
            #pragma unroll
            for (int nt = 0; nt < 4; ++nt)
                #pragma unroll
                for (int rr = 0; rr < 4; ++rr) acc[mt][nt][rr] = 0.f;
    };

    auto mfma_layer = [&](int layer) {
        #pragma unroll
        for (int kt = 0; kt < 2; ++kt) {
            bf16x8 ah[2], al[2];
            #pragma unroll
            for (int mt = 0; mt < 2; ++mt) {
                float4 a0, a1;
                if (layer == 0) {
                    long er = edge0 + wrow0 + mt * 16 + c15; if (er >= E) er = E - 1;
                    const float* p = e + er * 64 + kt * 32 + g * 8;
                    a0 = *(const float4*)p;
                    a1 = *(const float4*)(p + 4);
                } else {
                    int row = wrow0 + mt * 16 + c15;
                    int cb  = kt * 128 + g * 32;
                    a0 = *(const float4*)(lds + swz(row, cb));
                    a1 = *(const float4*)(lds + swz(row, cb + 16));
                }
                split8(a0, a1, ah[mt], al[mt]);
            }
            #pragma unroll
            for (int nt = 0; nt < 4; ++nt) {
                int fo = ((layer * 8 + kt * 4 + nt) * 64 + lane) * 8;
                bf16x8 bh = *(const bf16x8*)(whi + fo);
                bf16x8 bl = *(const bf16x8*)(wlo + fo);
                #pragma unroll
                for (int mt = 0; mt < 2; ++mt) {
                    acc[mt][nt] = __builtin_amdgcn_mfma_f32_16x16x32_bf16(ah[mt], bh, acc[mt][nt], 0, 0, 0);
                    acc[mt][nt] = __builtin_amdgcn_mfma_f32_16x16x32_bf16(ah[mt], bl, acc[mt][nt], 0, 0, 0);
                    acc[mt][nt] = __builtin_amdgcn_mfma_f32_16x16x32_bf16(al[mt], bh, acc[mt][nt], 0, 0, 0);
                }
            }
        }
    };

    auto writeback = [&](bool relu) {
        #pragma unroll
        for (int mt = 0; mt < 2; ++mt)
            #pragma unroll
            for (int nt = 0; nt < 4; ++nt)
                #pragma unroll
                for (int rr = 0; rr < 4; ++rr) {
                    int row  = wrow0 + mt * 16 + g * 4 + rr;
                    int colb = (nt * 16 + c15) * 4;
                    float v = acc[mt][nt][rr];
                    if (relu) v = fmaxf(v, 0.f);
                    *(float*)(lds + swz(row, colb)) = v;
                }
    };

    // L1: t1 = relu(e @ We1)
    zacc(); mfma_layer(0); writeback(true);
    // L2: z_e = t1 @ We2
    zacc(); mfma_layer(1);

    // attention: ae = z_e . Wa[0:64]; a = relu(ae + as[src] + ad[dst])
    #pragma unroll
    for (int mt = 0; mt < 2; ++mt) {
        float part[4];
        #pragma unroll
        for (int rr = 0; rr < 4; ++rr)
            part[rr] = acc[mt][0][rr] * waf[0] + acc[mt][1][rr] * waf[1]
                     + acc[mt][2][rr] * waf[2] + acc[mt][3][rr] * waf[3];
        #pragma unroll
        for (int off = 1; off < 16; off <<= 1)
            #pragma unroll
            for (int rr = 0; rr < 4; ++rr) part[rr] += __shfl_xor(part[rr], off);
        if (c15 == 0) {
            #pragma unroll
            for (int rr = 0; rr < 4; ++rr) {
                long er = edge0 + wrow0 + mt * 16 + g * 4 + rr; if (er >= E) er = E - 1;
                abuf[er] = fmaxf(part[rr] + asv[mt][rr], 0.f);
            }
        }
    }
    writeback(false);

    // L3: t2 = relu(z_e @ Wp1top + u_s[src] + u_d[dst] + bp1)
    // (u_s/u_d loaded at use — saves 32 VGPRs vs prefetch)
    zacc(); mfma_layer(2);
    #pragma unroll
    for (int mt = 0; mt < 2; ++mt)
        #pragma unroll
        for (int rr = 0; rr < 4; ++rr) {
            const float* us = u_s + (size_t)sn[mt][rr] * DIM;
            const float* ud = u_d + (size_t)dn[mt][rr] * DIM;
            #pragma unroll
            for (int nt = 0; nt < 4; ++nt)
                acc[mt][nt][rr] += us[nt * 16 + c15] + ud[nt * 16 + c15] + b1f[nt];
        }
    writeback(true);

    // L4: eproj = relu(t2 @ Wp2 + bp2)
    zacc(); mfma_layer(3);
    #pragma unroll
    for (int mt = 0; mt < 2; ++mt)
        #pragma unroll
        for (int nt = 0; nt < 4; ++nt)
            #pragma unroll
            for (int rr = 0; rr < 4; ++rr) {
                long er = edge0 + wrow0 + mt * 16 + g * 4 + rr; if (er >= E) er = E - 1;
                eproj[er * 64 + nt * 16 + c15] = fmaxf(acc[mt][nt][rr] + b2f[nt], 0.f);
            }
}

// ---- CSR build ----
__global__ __launch_bounds__(256) void k_hist(
    const int* __restrict__ dst, int* __restrict__ cnt, int E)
{
    int i = blockIdx.x * 256 + threadIdx.x;
    if (i < E) atomicAdd(&cnt[dst[i]], 1);
}

__global__ __launch_bounds__(256) void k_scan1(
    const int* __restrict__ cnt, int* __restrict__ ofs, int* __restrict__ bsum, int N)
{
    __shared__ int sm[256];
    int t = threadIdx.x, i = blockIdx.x * 256 + t;
    int v = (i < N) ? cnt[i] : 0;
    sm[t] = v;
    __syncthreads();
    #pragma unroll
    for (int off = 1; off < 256; off <<= 1) {
        int tmp = (t >= off) ? sm[t - off] : 0;
        __syncthreads();
        sm[t] += tmp;
        __syncthreads();
    }
    if (i < N) ofs[i] = sm[t] - v;
    if (t == 255) bsum[blockIdx.x] = sm[255];
}

__global__ __launch_bounds__(256) void k_scan2(int* __restrict__ bsum, int NB)
{
    __shared__ int sm[256];
    int t = threadIdx.x;
    int v = (t < NB) ? bsum[t] : 0;
    sm[t] = v;
    __syncthreads();
    #pragma unroll
    for (int off = 1; off < 256; off <<= 1) {
        int tmp = (t >= off) ? sm[t - off] : 0;
        __syncthreads();
        sm[t] += tmp;
        __syncthreads();
    }
    if (t < NB) bsum[t] = sm[t] - v;   // exclusive
}

__global__ __launch_bounds__(256) void k_scan3(
    int* __restrict__ ofs, int* __restrict__ cursor,
    const int* __restrict__ bsum, int N)
{
    int i = blockIdx.x * 256 + threadIdx.x;
    if (i < N) {
        int o = ofs[i] + bsum[blockIdx.x];
        ofs[i] = o;
        cursor[i] = o;
    }
}

// ---- fused segment softmax + weighted gather: 1 wave/node.
// Fast path (deg<=64): lane-parallel loads; gather loop runs a UNIFORM trip
// count so every __shfl source lane is active (divergent trip counts made
// ds_bpermute read inactive lanes -> 0 -> dropped edges; R5 bug).
__global__ __launch_bounds__(256) void k_aggregate(
    const float* __restrict__ abuf, const int* __restrict__ eidx,
    const int* __restrict__ ofs, const int* __restrict__ cnt,
    const int* __restrict__ src, const float* __restrict__ z_h,
    float* __restrict__ hout, int N)
{
    int wid  = (blockIdx.x * 256 + threadIdx.x) >> 6;
    int lane = threadIdx.x & 63;
    if (wid >= N) return;
    int grp = lane >> 4, c15 = lane & 15;

    int begin = ofs[wid];
    int deg   = cnt[wid];

    float4 acc = make_float4(0.f, 0.f, 0.f, 0.f);
    float inv_s;

    if (deg <= 64) {
        float a = 0.f; int sidx = 0;
        if (lane < deg) {
            int eid = eidx[begin + lane];
            a    = abuf[eid];
            sidx = src[eid];
        }
        // max (scores >= 0; extra lanes contribute 0 which matches reference)
        float m = a;
        #pragma unroll
        for (int off = 32; off; off >>= 1) m = fmaxf(m, __shfl_xor(m, off));

        float ex = (lane < deg) ? __expf(a - m) : 0.f;
        float s = ex;
        #pragma unroll
        for (int off = 32; off; off >>= 1) s += __shfl_xor(s, off);
        inv_s = 1.0f / fmaxf(s, 1e-9f);

        // uniform trip count: all 64 lanes execute every __shfl
        int trips = (deg + 3) >> 2;
        for (int i = 0; i < trips; ++i) {
            int k = grp + 4 * i;
            float w  = __shfl(ex,   k & 63);
            int   sk = __shfl(sidx, k & 63);
            if (k < deg) {
                const float4 v = *(const float4*)(z_h + (size_t)sk * DIM + c15 * 4);
                acc.x = fmaf(w, v.x, acc.x);
                acc.y = fmaf(w, v.y, acc.y);
                acc.z = fmaf(w, v.z, acc.z);
                acc.w = fmaf(w, v.w, acc.w);
            }
        }
    } else {
        float m = 0.f;
        for (int k = lane; k < deg; k += 64) m = fmaxf(m, abuf[eidx[begin + k]]);
        #pragma unroll
        for (int off = 32; off; off >>= 1) m = fmaxf(m, __shfl_xor(m, off));

        float s = 0.f;
        for (int k = lane; k < deg; k += 64) s += __expf(abuf[eidx[begin + k]] - m);
        #pragma unroll
        for (int off = 32; off; off >>= 1) s += __shfl_xor(s, off);
        inv_s = 1.0f / fmaxf(s, 1e-9f);

        for (int k = grp; k < deg; k += 4) {
            int eid = eidx[begin + k];
            float w = __expf(abuf[eid] - m);
            const float4 v = *(const float4*)(z_h + (size_t)src[eid] * DIM + c15 * 4);
            acc.x = fmaf(w, v.x, acc.x);
            acc.y = fmaf(w, v.y, acc.y);
            acc.z = fmaf(w, v.z, acc.z);
            acc.w = fmaf(w, v.w, acc.w);
        }
    }

    // combine the 4 groups (lanes l, l+16, l+32, l+48 hold same features)
    #pragma unroll
    for (int off = 16; off <= 32; off <<= 1) {
        acc.x += __shfl_xor(acc.x, off);
        acc.y += __shfl_xor(acc.y, off);
        acc.z += __shfl_xor(acc.z, off);
        acc.w += __shfl_xor(acc.w, off);
    }
    if (grp == 0) {
        float4 r = make_float4(fmaxf(acc.x * inv_s, 0.f), fmaxf(acc.y * inv_s, 0.f),
                               fmaxf(acc.z * inv_s, 0.f), fmaxf(acc.w * inv_s, 0.f));
        *(float4*)(hout + (size_t)wid * DIM + c15 * 4) = r;
    }
}

extern "C" void kernel_launch(void* const* d_in, const int* in_sizes, int n_in,
                              void* d_out, int out_size, void* d_ws, size_t ws_size,
                              hipStream_t stream)
{
    const float* h   = (const float*)d_in[0];
    const float* e   = (const float*)d_in[1];
    const int*   src = (const int*)d_in[2];
    const int*   dst = (const int*)d_in[3];
    const float* Wh1 = (const float*)d_in[4];
    const float* Wh2 = (const float*)d_in[5];
    const float* We1 = (const float*)d_in[6];
    const float* We2 = (const float*)d_in[7];
    const float* Wp1 = (const float*)d_in[8];
    const float* bp1 = (const float*)d_in[9];
    const float* Wp2 = (const float*)d_in[10];
    const float* bp2 = (const float*)d_in[11];
    const float* Wa  = (const float*)d_in[12];

    const int N = in_sizes[0] / DIM;
    const int E = in_sizes[1] / DIM;

    float* ws   = (float*)d_ws;
    float* z_h  = ws;  ws += (size_t)N * DIM;
    float* u_s  = ws;  ws += (size_t)N * DIM;
    float* u_d  = ws;  ws += (size_t)N * DIM;
    float* as_  = ws;  ws += N;
    float* ad_  = ws;  ws += N;
    float* abuf = ws;  ws += E;
    int* cnt    = (int*)ws;  ws += N;
    int* ofs    = (int*)ws;  ws += N;
    int* cursor = (int*)ws;  ws += N;
    int* eidx   = (int*)ws;  ws += E;
    int* bsum   = (int*)ws;  ws += 256;
    unsigned short* whi = (unsigned short*)ws;  ws += 32768 / 2;
    unsigned short* wlo = (unsigned short*)ws;  ws += 32768 / 2;

    float* hout  = (float*)d_out;
    float* eproj = hout + (size_t)N * DIM;

    const int NB = (N + 255) / 256;   // N=50000 -> 196 <= 256

    hipMemsetAsync(cnt, 0, (size_t)N * sizeof(int), stream);

    k_prep<<<128, 256, 0, stream>>>(We1, We2, Wp1, Wp2, Wh1, Wh2, whi, wlo);

    // CSR counts/offsets first so edge_mfma can do the fill itself
    k_hist<<<(E + 255) / 256, 256, 0, stream>>>(dst, cnt, E);
    k_scan1<<<NB, 256, 0, stream>>>(cnt, ofs, bsum, N);
    k_scan2<<<1, 256, 0, stream>>>(bsum, NB);
    k_scan3<<<NB, 256, 0, stream>>>(ofs, cursor, bsum, N);

    node_mfma<<<(N + BM - 1) / BM, 256, 0, stream>>>(
        h, whi, wlo, Wa, z_h, u_s, u_d, as_, ad_, N);

    edge_mfma<<<(E + BM - 1) / BM, 256, 0, stream>>>(
        e, src, dst, u_s, u_d, as_, ad_, whi, wlo, Wa, bp1, bp2,
        eproj, abuf, cursor, eidx, E);

    k_aggregate<<<((N * 64) + 255) / 256, 256, 0, stream>>>(
        abuf, eidx, ofs, cnt, src, z_h, hout, N);
}

// Round 7
// 380.261 us; speedup vs baseline: 3.6141x; 1.0005x over previous
//
#include <hip/hip_runtime.h>
#include <hip/hip_bf16.h>

#define DIM 64
#define BM 128

typedef __attribute__((ext_vector_type(8))) short bf16x8;
typedef __attribute__((ext_vector_type(4))) float f32x4;

__device__ __forceinline__ short f2bf_hw(float x) {
    __hip_bfloat16 b = __float2bfloat16(x);
    return (short)reinterpret_cast<unsigned short&>(b);
}
__device__ __forceinline__ float bf2f_hw(short s) {
    unsigned u = ((unsigned)(unsigned short)s) << 16;
    return __uint_as_float(u);
}
__device__ __forceinline__ void split8(float4 a, float4 b, bf16x8& hi, bf16x8& lo) {
    float v[8] = {a.x, a.y, a.z, a.w, b.x, b.y, b.z, b.w};
    #pragma unroll
    for (int i = 0; i < 8; ++i) {
        short h = f2bf_hw(v[i]);
        hi[i] = h;
        lo[i] = f2bf_hw(v[i] - bf2f_hw(h));
    }
}
// XOR-swizzle (T2): byte address within act tile; row stride 256B
__device__ __forceinline__ int swz(int row, int colbyte) {
    return row * 256 + (colbyte ^ ((row & 7) << 4));
}

// ---- weight prep: 8 layers (0..3 edge: We1,We2,Wp1top,Wp2; 4..7 node:
// Wh1,Wh2,Wp1mid,Wp1bot), split hi/lo bf16, MFMA B-fragment order:
// w[layer][kt][nt][lane][e], k = kt*32+(lane>>4)*8+e, n = nt*16+(lane&15)
__global__ __launch_bounds__(256) void k_prep(
    const float* __restrict__ We1, const float* __restrict__ We2,
    const float* __restrict__ Wp1, const float* __restrict__ Wp2,
    const float* __restrict__ Wh1, const float* __restrict__ Wh2,
    unsigned short* __restrict__ whi, unsigned short* __restrict__ wlo)
{
    int t = blockIdx.x * 256 + threadIdx.x;     // 0..32767
    int e_ = t & 7, lane = (t >> 3) & 63, frag = (t >> 9) & 7, layer = t >> 12;
    int kt = frag >> 2, nt = frag & 3;
    int k = kt * 32 + ((lane >> 4) * 8) + e_;
    int n = nt * 16 + (lane & 15);
    const float* W;
    switch (layer) {
        case 0: W = We1; break;
        case 1: W = We2; break;
        case 2: W = Wp1; break;
        case 3: W = Wp2; break;
        case 4: W = Wh1; break;
        case 5: W = Wh2; break;
        case 6: W = Wp1 + 64 * 64; break;
        default: W = Wp1 + 128 * 64; break;
    }
    float w = W[k * 64 + n];
    short h = f2bf_hw(w);
    whi[t] = (unsigned short)h;
    wlo[t] = (unsigned short)f2bf_hw(w - bf2f_hw(h));
}

// ---- node pipeline via MFMA: 128 nodes/block, 4 waves x 32 wave-private rows
__global__ __launch_bounds__(256) void node_mfma(
    const float* __restrict__ h,
    const unsigned short* __restrict__ whi, const unsigned short* __restrict__ wlo,
    const float* __restrict__ Wa,
    float* __restrict__ z_h, float* __restrict__ u_s, float* __restrict__ u_d,
    float* __restrict__ as_, float* __restrict__ ad_, int N)
{
    __shared__ float act[BM * 64];
    char* lds = (char*)act;
    const int lane  = threadIdx.x & 63;
    const int wave  = threadIdx.x >> 6;
    const int wrow0 = wave * 32;
    const long node0 = (long)blockIdx.x * BM;
    const int g   = lane >> 4;
    const int c15 = lane & 15;

    float was[4], wad[4];
    #pragma unroll
    for (int nt = 0; nt < 4; ++nt) {
        was[nt] = Wa[64  + nt * 16 + c15];
        wad[nt] = Wa[128 + nt * 16 + c15];
    }

    f32x4 acc[2][4];
    auto zacc = [&]() {
        #pragma unroll
        for (int mt = 0; mt < 2; ++mt)
            #pragma unroll
            for (int nt = 0; nt < 4; ++nt)
                #pragma unroll
                for (int rr = 0; rr < 4; ++rr) acc[mt][nt][rr] = 0.f;
    };

    auto mfma_layer = [&](int layer) {
        #pragma unroll
        for (int kt = 0; kt < 2; ++kt) {
            bf16x8 ah[2], al[2];
            #pragma unroll
            for (int mt = 0; mt < 2; ++mt) {
                float4 a0, a1;
                if (layer == 4) {           // A from global h
                    long nr = node0 + wrow0 + mt * 16 + c15; if (nr >= N) nr = N - 1;
                    const float* p = h + nr * 64 + kt * 32 + g * 8;
                    a0 = *(const float4*)p;
                    a1 = *(const float4*)(p + 4);
                } else {
                    int row = wrow0 + mt * 16 + c15;
                    int cb  = kt * 128 + g * 32;
                    a0 = *(const float4*)(lds + swz(row, cb));
                    a1 = *(const float4*)(lds + swz(row, cb + 16));
                }
                split8(a0, a1, ah[mt], al[mt]);
            }
            #pragma unroll
            for (int nt = 0; nt < 4; ++nt) {
                int fo = ((layer * 8 + kt * 4 + nt) * 64 + lane) * 8;
                bf16x8 bh = *(const bf16x8*)(whi + fo);
                bf16x8 bl = *(const bf16x8*)(wlo + fo);
                #pragma unroll
                for (int mt = 0; mt < 2; ++mt) {
                    acc[mt][nt] = __builtin_amdgcn_mfma_f32_16x16x32_bf16(ah[mt], bh, acc[mt][nt], 0, 0, 0);
                    acc[mt][nt] = __builtin_amdgcn_mfma_f32_16x16x32_bf16(ah[mt], bl, acc[mt][nt], 0, 0, 0);
                    acc[mt][nt] = __builtin_amdgcn_mfma_f32_16x16x32_bf16(al[mt], bh, acc[mt][nt], 0, 0, 0);
                }
            }
        }
    };

    auto writeback = [&](bool relu) {
        #pragma unroll
        for (int mt = 0; mt < 2; ++mt)
            #pragma unroll
            for (int nt = 0; nt < 4; ++nt)
                #pragma unroll
                for (int rr = 0; rr < 4; ++rr) {
                    int row  = wrow0 + mt * 16 + g * 4 + rr;
                    int colb = (nt * 16 + c15) * 4;
                    float v = acc[mt][nt][rr];
                    if (relu) v = fmaxf(v, 0.f);
                    *(float*)(lds + swz(row, colb)) = v;
                }
    };

    auto store_global = [&](float* __restrict__ out) {
        #pragma unroll
        for (int mt = 0; mt < 2; ++mt)
            #pragma unroll
            for (int nt = 0; nt < 4; ++nt)
                #pragma unroll
                for (int rr = 0; rr < 4; ++rr) {
                    long nr = node0 + wrow0 + mt * 16 + g * 4 + rr; if (nr >= N) nr = N - 1;
                    out[nr * 64 + nt * 16 + c15] = acc[mt][nt][rr];
                }
    };

    // L1: t1 = relu(h @ Wh1)
    zacc(); mfma_layer(4); writeback(true);
    // L2: z_h = t1 @ Wh2
    zacc(); mfma_layer(5);

    // as = z_h . Wa[64:128], ad = z_h . Wa[128:192]
    #pragma unroll
    for (int mt = 0; mt < 2; ++mt) {
        float ps[4], pd[4];
        #pragma unroll
        for (int rr = 0; rr < 4; ++rr) {
            ps[rr] = acc[mt][0][rr] * was[0] + acc[mt][1][rr] * was[1]
                   + acc[mt][2][rr] * was[2] + acc[mt][3][rr] * was[3];
            pd[rr] = acc[mt][0][rr] * wad[0] + acc[mt][1][rr] * wad[1]
                   + acc[mt][2][rr] * wad[2] + acc[mt][3][rr] * wad[3];
        }
        #pragma unroll
        for (int off = 1; off < 16; off <<= 1)
            #pragma unroll
            for (int rr = 0; rr < 4; ++rr) {
                ps[rr] += __shfl_xor(ps[rr], off);
                pd[rr] += __shfl_xor(pd[rr], off);
            }
        if (c15 == 0) {
            #pragma unroll
            for (int rr = 0; rr < 4; ++rr) {
                long nr = node0 + wrow0 + mt * 16 + g * 4 + rr; if (nr >= N) nr = N - 1;
                as_[nr] = ps[rr];
                ad_[nr] = pd[rr];
            }
        }
    }
    store_global(z_h);
    writeback(false);   // z_h -> LDS for L3/L4

    // L3: u_s = z_h @ Wp1[64:128]
    zacc(); mfma_layer(6); store_global(u_s);
    // L4: u_d = z_h @ Wp1[128:192]  (LDS still holds z_h)
    zacc(); mfma_layer(7); store_global(u_d);
}

// ---- edge pipeline: split-bf16 MFMA chain, wave-private rows, no barriers.
// uv/asv gathers issued at kernel start (latency hidden under L1/L2 MFMA —
// R6 showed removing this costs ~60µs). CSR fill fused (cursor ready at launch).
__global__ __launch_bounds__(256) void edge_mfma(
    const float* __restrict__ e, const int* __restrict__ src, const int* __restrict__ dst,
    const float* __restrict__ u_s, const float* __restrict__ u_d,
    const float* __restrict__ as_, const float* __restrict__ ad_,
    const unsigned short* __restrict__ whi, const unsigned short* __restrict__ wlo,
    const float* __restrict__ Wa, const float* __restrict__ bp1, const float* __restrict__ bp2,
    float* __restrict__ eproj, float* __restrict__ abuf,
    int* __restrict__ cursor, int* __restrict__ eidx, int E)
{
    __shared__ float act[BM * 64];
    char* lds = (char*)act;
    const int lane  = threadIdx.x & 63;
    const int wave  = threadIdx.x >> 6;
    const int wrow0 = wave * 32;
    const long edge0 = (long)blockIdx.x * BM;
    const int g   = lane >> 4;
    const int c15 = lane & 15;

    int sn[2][4], dn[2][4];
    #pragma unroll
    for (int mt = 0; mt < 2; ++mt)
        #pragma unroll
        for (int rr = 0; rr < 4; ++rr) {
            long er0 = edge0 + wrow0 + mt * 16 + g * 4 + rr;
            long er = er0 >= E ? E - 1 : er0;
            sn[mt][rr] = src[er]; dn[mt][rr] = dst[er];
            // fused CSR fill (one lane per row)
            if (c15 == 0 && er0 < E) {
                int p = atomicAdd(&cursor[dn[mt][rr]], 1);
                eidx[p] = (int)er0;
            }
        }

    float waf[4], b1f[4], b2f[4];
    #pragma unroll
    for (int nt = 0; nt < 4; ++nt) {
        waf[nt] = Wa[nt * 16 + c15];
        b1f[nt] = bp1[nt * 16 + c15];
        b2f[nt] = bp2[nt * 16 + c15];
    }

    // prefetch per-edge gathers early (consumed at attention / L3 accumulate)
    float uv[2][4][4], asv[2][4];
    #pragma unroll
    for (int mt = 0; mt < 2; ++mt)
        #pragma unroll
        for (int rr = 0; rr < 4; ++rr) {
            const float* us = u_s + (size_t)sn[mt][rr] * DIM;
            const float* ud = u_d + (size_t)dn[mt][rr] * DIM;
            #pragma unroll
            for (int nt = 0; nt < 4; ++nt)
                uv[mt][nt][rr] = us[nt * 16 + c15] + ud[nt * 16 + c15] + b1f[nt];
            asv[mt][rr] = as_[sn[mt][rr]] + ad_[dn[mt][rr]];
        }

    f32x4 acc[2][4];
    auto zacc = [&]() {
        #pragma unroll
        for (int mt = 0; mt < 2; ++mt)
            #pragma unroll
            for (int nt = 0; nt < 4; ++nt)
                #pragma unroll
                for (int rr = 0; rr < 4; ++rr) acc[mt][nt][rr] = 0.f;
    };

    auto mfma_layer = [&](int layer) {
        #pragma unroll
        for (int kt = 0; kt < 2; ++kt) {
            bf16x8 ah[2], al[2];
            #pragma unroll
            for (int mt = 0; mt < 2; ++mt) {
                float4 a0, a1;
                if (layer == 0) {
                    long er = edge0 + wrow0 + mt * 16 + c15; if (er >= E) er = E - 1;
                    const float* p = e + er * 64 + kt * 32 + g * 8;
                    a0 = *(const float4*)p;
                    a1 = *(const float4*)(p + 4);
                } else {
                    int row = wrow0 + mt * 16 + c15;
                    int cb  = kt * 128 + g * 32;
                    a0 = *(const float4*)(lds + swz(row, cb));
                    a1 = *(const float4*)(lds + swz(row, cb + 16));
                }
                split8(a0, a1, ah[mt], al[mt]);
            }
            #pragma unroll
            for (int nt = 0; nt < 4; ++nt) {
                int fo = ((layer * 8 + kt * 4 + nt) * 64 + lane) * 8;
                bf16x8 bh = *(const bf16x8*)(whi + fo);
                bf16x8 bl = *(const bf16x8*)(wlo + fo);
                #pragma unroll
                for (int mt = 0; mt < 2; ++mt) {
                    acc[mt][nt] = __builtin_amdgcn_mfma_f32_16x16x32_bf16(ah[mt], bh, acc[mt][nt], 0, 0, 0);
                    acc[mt][nt] = __builtin_amdgcn_mfma_f32_16x16x32_bf16(ah[mt], bl, acc[mt][nt], 0, 0, 0);
                    acc[mt][nt] = __builtin_amdgcn_mfma_f32_16x16x32_bf16(al[mt], bh, acc[mt][nt], 0, 0, 0);
                }
            }
        }
    };

    auto writeback = [&](bool relu) {
        #pragma unroll
        for (int mt = 0; mt < 2; ++mt)
            #pragma unroll
            for (int nt = 0; nt < 4; ++nt)
                #pragma unroll
                for (int rr = 0; rr < 4; ++rr) {
                    int row  = wrow0 + mt * 16 + g * 4 + rr;
                    int colb = (nt * 16 + c15) * 4;
                    float v = acc[mt][nt][rr];
                    if (relu) v = fmaxf(v, 0.f);
                    *(float*)(lds + swz(row, colb)) = v;
                }
    };

    // L1: t1 = relu(e @ We1)
    zacc(); mfma_layer(0); writeback(true);
    // L2: z_e = t1 @ We2
    zacc(); mfma_layer(1);

    // attention: ae = z_e . Wa[0:64]; a = relu(ae + as[src] + ad[dst])
    #pragma unroll
    for (int mt = 0; mt < 2; ++mt) {
        float part[4];
        #pragma unroll
        for (int rr = 0; rr < 4; ++rr)
            part[rr] = acc[mt][0][rr] * waf[0] + acc[mt][1][rr] * waf[1]
                     + acc[mt][2][rr] * waf[2] + acc[mt][3][rr] * waf[3];
        #pragma unroll
        for (int off = 1; off < 16; off <<= 1)
            #pragma unroll
            for (int rr = 0; rr < 4; ++rr) part[rr] += __shfl_xor(part[rr], off);
        if (c15 == 0) {
            #pragma unroll
            for (int rr = 0; rr < 4; ++rr) {
                long er = edge0 + wrow0 + mt * 16 + g * 4 + rr; if (er >= E) er = E - 1;
                abuf[er] = fmaxf(part[rr] + asv[mt][rr], 0.f);
            }
        }
    }
    writeback(false);

    // L3: t2 = relu(z_e @ Wp1top + uv + bp1)   (uv prefetched at start)
    zacc(); mfma_layer(2);
    #pragma unroll
    for (int mt = 0; mt < 2; ++mt)
        #pragma unroll
        for (int nt = 0; nt < 4; ++nt)
            #pragma unroll
            for (int rr = 0; rr < 4; ++rr)
                acc[mt][nt][rr] += uv[mt][nt][rr];
    writeback(true);

    // L4: eproj = relu(t2 @ Wp2 + bp2)
    zacc(); mfma_layer(3);
    #pragma unroll
    for (int mt = 0; mt < 2; ++mt)
        #pragma unroll
        for (int nt = 0; nt < 4; ++nt)
            #pragma unroll
            for (int rr = 0; rr < 4; ++rr) {
                long er = edge0 + wrow0 + mt * 16 + g * 4 + rr; if (er >= E) er = E - 1;
                eproj[er * 64 + nt * 16 + c15] = fmaxf(acc[mt][nt][rr] + b2f[nt], 0.f);
            }
}

// ---- CSR build ----
__global__ __launch_bounds__(256) void k_hist(
    const int* __restrict__ dst, int* __restrict__ cnt, int E)
{
    int i = blockIdx.x * 256 + threadIdx.x;
    if (i < E) atomicAdd(&cnt[dst[i]], 1);
}

__global__ __launch_bounds__(256) void k_scan1(
    const int* __restrict__ cnt, int* __restrict__ ofs, int* __restrict__ bsum, int N)
{
    __shared__ int sm[256];
    int t = threadIdx.x, i = blockIdx.x * 256 + t;
    int v = (i < N) ? cnt[i] : 0;
    sm[t] = v;
    __syncthreads();
    #pragma unroll
    for (int off = 1; off < 256; off <<= 1) {
        int tmp = (t >= off) ? sm[t - off] : 0;
        __syncthreads();
        sm[t] += tmp;
        __syncthreads();
    }
    if (i < N) ofs[i] = sm[t] - v;
    if (t == 255) bsum[blockIdx.x] = sm[255];
}

__global__ __launch_bounds__(256) void k_scan2(int* __restrict__ bsum, int NB)
{
    __shared__ int sm[256];
    int t = threadIdx.x;
    int v = (t < NB) ? bsum[t] : 0;
    sm[t] = v;
    __syncthreads();
    #pragma unroll
    for (int off = 1; off < 256; off <<= 1) {
        int tmp = (t >= off) ? sm[t - off] : 0;
        __syncthreads();
        sm[t] += tmp;
        __syncthreads();
    }
    if (t < NB) bsum[t] = sm[t] - v;   // exclusive
}

__global__ __launch_bounds__(256) void k_scan3(
    int* __restrict__ ofs, int* __restrict__ cursor,
    const int* __restrict__ bsum, int N)
{
    int i = blockIdx.x * 256 + threadIdx.x;
    if (i < N) {
        int o = ofs[i] + bsum[blockIdx.x];
        ofs[i] = o;
        cursor[i] = o;
    }
}

// ---- fused segment softmax + weighted gather: 1 wave/node.
// Fast path (deg<=64): lane-parallel loads; gather loop runs a UNIFORM trip
// count so every __shfl source lane is active.
__global__ __launch_bounds__(256) void k_aggregate(
    const float* __restrict__ abuf, const int* __restrict__ eidx,
    const int* __restrict__ ofs, const int* __restrict__ cnt,
    const int* __restrict__ src, const float* __restrict__ z_h,
    float* __restrict__ hout, int N)
{
    int wid  = (blockIdx.x * 256 + threadIdx.x) >> 6;
    int lane = threadIdx.x & 63;
    if (wid >= N) return;
    int grp = lane >> 4, c15 = lane & 15;

    int begin = ofs[wid];
    int deg   = cnt[wid];

    float4 acc = make_float4(0.f, 0.f, 0.f, 0.f);
    float inv_s;

    if (deg <= 64) {
        float a = 0.f; int sidx = 0;
        if (lane < deg) {
            int eid = eidx[begin + lane];
            a    = abuf[eid];
            sidx = src[eid];
        }
        float m = a;
        #pragma unroll
        for (int off = 32; off; off >>= 1) m = fmaxf(m, __shfl_xor(m, off));

        float ex = (lane < deg) ? __expf(a - m) : 0.f;
        float s = ex;
        #pragma unroll
        for (int off = 32; off; off >>= 1) s += __shfl_xor(s, off);
        inv_s = 1.0f / fmaxf(s, 1e-9f);

        int trips = (deg + 3) >> 2;
        for (int i = 0; i < trips; ++i) {
            int k = grp + 4 * i;
            float w  = __shfl(ex,   k & 63);
            int   sk = __shfl(sidx, k & 63);
            if (k < deg) {
                const float4 v = *(const float4*)(z_h + (size_t)sk * DIM + c15 * 4);
                acc.x = fmaf(w, v.x, acc.x);
                acc.y = fmaf(w, v.y, acc.y);
                acc.z = fmaf(w, v.z, acc.z);
                acc.w = fmaf(w, v.w, acc.w);
            }
        }
    } else {
        float m = 0.f;
        for (int k = lane; k < deg; k += 64) m = fmaxf(m, abuf[eidx[begin + k]]);
        #pragma unroll
        for (int off = 32; off; off >>= 1) m = fmaxf(m, __shfl_xor(m, off));

        float s = 0.f;
        for (int k = lane; k < deg; k += 64) s += __expf(abuf[eidx[begin + k]] - m);
        #pragma unroll
        for (int off = 32; off; off >>= 1) s += __shfl_xor(s, off);
        inv_s = 1.0f / fmaxf(s, 1e-9f);

        for (int k = grp; k < deg; k += 4) {
            int eid = eidx[begin + k];
            float w = __expf(abuf[eid] - m);
            const float4 v = *(const float4*)(z_h + (size_t)src[eid] * DIM + c15 * 4);
            acc.x = fmaf(w, v.x, acc.x);
            acc.y = fmaf(w, v.y, acc.y);
            acc.z = fmaf(w, v.z, acc.z);
            acc.w = fmaf(w, v.w, acc.w);
        }
    }

    #pragma unroll
    for (int off = 16; off <= 32; off <<= 1) {
        acc.x += __shfl_xor(acc.x, off);
        acc.y += __shfl_xor(acc.y, off);
        acc.z += __shfl_xor(acc.z, off);
        acc.w += __shfl_xor(acc.w, off);
    }
    if (grp == 0) {
        float4 r = make_float4(fmaxf(acc.x * inv_s, 0.f), fmaxf(acc.y * inv_s, 0.f),
                               fmaxf(acc.z * inv_s, 0.f), fmaxf(acc.w * inv_s, 0.f));
        *(float4*)(hout + (size_t)wid * DIM + c15 * 4) = r;
    }
}

extern "C" void kernel_launch(void* const* d_in, const int* in_sizes, int n_in,
                              void* d_out, int out_size, void* d_ws, size_t ws_size,
                              hipStream_t stream)
{
    const float* h   = (const float*)d_in[0];
    const float* e   = (const float*)d_in[1];
    const int*   src = (const int*)d_in[2];
    const int*   dst = (const int*)d_in[3];
    const float* Wh1 = (const float*)d_in[4];
    const float* Wh2 = (const float*)d_in[5];
    const float* We1 = (const float*)d_in[6];
    const float* We2 = (const float*)d_in[7];
    const float* Wp1 = (const float*)d_in[8];
    const float* bp1 = (const float*)d_in[9];
    const float* Wp2 = (const float*)d_in[10];
    const float* bp2 = (const float*)d_in[11];
    const float* Wa  = (const float*)d_in[12];

    const int N = in_sizes[0] / DIM;
    const int E = in_sizes[1] / DIM;

    float* ws   = (float*)d_ws;
    float* z_h  = ws;  ws += (size_t)N * DIM;
    float* u_s  = ws;  ws += (size_t)N * DIM;
    float* u_d  = ws;  ws += (size_t)N * DIM;
    float* as_  = ws;  ws += N;
    float* ad_  = ws;  ws += N;
    float* abuf = ws;  ws += E;
    int* cnt    = (int*)ws;  ws += N;
    int* ofs    = (int*)ws;  ws += N;
    int* cursor = (int*)ws;  ws += N;
    int* eidx   = (int*)ws;  ws += E;
    int* bsum   = (int*)ws;  ws += 256;
    unsigned short* whi = (unsigned short*)ws;  ws += 32768 / 2;
    unsigned short* wlo = (unsigned short*)ws;  ws += 32768 / 2;

    float* hout  = (float*)d_out;
    float* eproj = hout + (size_t)N * DIM;

    const int NB = (N + 255) / 256;   // N=50000 -> 196 <= 256

    hipMemsetAsync(cnt, 0, (size_t)N * sizeof(int), stream);

    k_prep<<<128, 256, 0, stream>>>(We1, We2, Wp1, Wp2, Wh1, Wh2, whi, wlo);

    // CSR counts/offsets first so edge_mfma can do the fill itself
    k_hist<<<(E + 255) / 256, 256, 0, stream>>>(dst, cnt, E);
    k_scan1<<<NB, 256, 0, stream>>>(cnt, ofs, bsum, N);
    k_scan2<<<1, 256, 0, stream>>>(bsum, NB);
    k_scan3<<<NB, 256, 0, stream>>>(ofs, cursor, bsum, N);

    node_mfma<<<(N + BM - 1) / BM, 256, 0, stream>>>(
        h, whi, wlo, Wa, z_h, u_s, u_d, as_, ad_, N);

    edge_mfma<<<(E + BM - 1) / BM, 256, 0, stream>>>(
        e, src, dst, u_s, u_d, as_, ad_, whi, wlo, Wa, bp1, bp2,
        eproj, abuf, cursor, eidx, E);

    k_aggregate<<<((N * 64) + 255) / 256, 256, 0, stream>>>(
        abuf, eidx, ofs, cnt, src, z_h, hout, N);
}

// Round 9
// 347.723 us; speedup vs baseline: 3.9523x; 1.0936x over previous
//
#include <hip/hip_runtime.h>
#include <hip/hip_bf16.h>

#define DIM 64
#define BM 128

typedef __attribute__((ext_vector_type(8))) short bf16x8;
typedef __attribute__((ext_vector_type(4))) float f32x4;

__device__ __forceinline__ short f2bf_hw(float x) {
    __hip_bfloat16 b = __float2bfloat16(x);
    return (short)reinterpret_cast<unsigned short&>(b);
}
__device__ __forceinline__ float bf2f_hw(short s) {
    unsigned u = ((unsigned)(unsigned short)s) << 16;
    return __uint_as_float(u);
}
__device__ __forceinline__ void split8(f32x4 a, f32x4 b, bf16x8& hi, bf16x8& lo) {
    float v[8] = {a[0], a[1], a[2], a[3], b[0], b[1], b[2], b[3]};
    #pragma unroll
    for (int i = 0; i < 8; ++i) {
        short h = f2bf_hw(v[i]);
        hi[i] = h;
        lo[i] = f2bf_hw(v[i] - bf2f_hw(h));
    }
}
// XOR-swizzle (T2): byte address within act tile; row stride 256B
__device__ __forceinline__ int swz(int row, int colbyte) {
    return row * 256 + (colbyte ^ ((row & 7) << 4));
}

// ---- weight prep: 8 layers (0..3 edge: We1,We2,Wp1top,Wp2; 4..7 node:
// Wh1,Wh2,Wp1mid,Wp1bot), split hi/lo bf16, MFMA B-fragment order:
// w[layer][kt][nt][lane][e], k = kt*32+(lane>>4)*8+e, n = nt*16+(lane&15)
__global__ __launch_bounds__(256) void k_prep(
    const float* __restrict__ We1, const float* __restrict__ We2,
    const float* __restrict__ Wp1, const float* __restrict__ Wp2,
    const float* __restrict__ Wh1, const float* __restrict__ Wh2,
    unsigned short* __restrict__ whi, unsigned short* __restrict__ wlo)
{
    int t = blockIdx.x * 256 + threadIdx.x;     // 0..32767
    int e_ = t & 7, lane = (t >> 3) & 63, frag = (t >> 9) & 7, layer = t >> 12;
    int kt = frag >> 2, nt = frag & 3;
    int k = kt * 32 + ((lane >> 4) * 8) + e_;
    int n = nt * 16 + (lane & 15);
    const float* W;
    switch (layer) {
        case 0: W = We1; break;
        case 1: W = We2; break;
        case 2: W = Wp1; break;
        case 3: W = Wp2; break;
        case 4: W = Wh1; break;
        case 5: W = Wh2; break;
        case 6: W = Wp1 + 64 * 64; break;
        default: W = Wp1 + 128 * 64; break;
    }
    float w = W[k * 64 + n];
    short h = f2bf_hw(w);
    whi[t] = (unsigned short)h;
    wlo[t] = (unsigned short)f2bf_hw(w - bf2f_hw(h));
}

// ---- node pipeline via MFMA: 128 nodes/block, 4 waves x 32 wave-private rows
__global__ __launch_bounds__(256) void node_mfma(
    const float* __restrict__ h,
    const unsigned short* __restrict__ whi, const unsigned short* __restrict__ wlo,
    const float* __restrict__ Wa,
    float* __restrict__ z_h, float* __restrict__ u_s, float* __restrict__ u_d,
    float* __restrict__ as_, float* __restrict__ ad_, int N)
{
    __shared__ float act[BM * 64];
    char* lds = (char*)act;
    const int lane  = threadIdx.x & 63;
    const int wave  = threadIdx.x >> 6;
    const int wrow0 = wave * 32;
    const long node0 = (long)blockIdx.x * BM;
    const int g   = lane >> 4;
    const int c15 = lane & 15;

    float was[4], wad[4];
    #pragma unroll
    for (int nt = 0; nt < 4; ++nt) {
        was[nt] = Wa[64  + nt * 16 + c15];
        wad[nt] = Wa[128 + nt * 16 + c15];
    }

    f32x4 acc[2][4];
    auto zacc = [&]() {
        #pragma unroll
        for (int mt = 0; mt < 2; ++mt)
            #pragma unroll
            for (int nt = 0; nt < 4; ++nt)
                #pragma unroll
                for (int rr = 0; rr < 4; ++rr) acc[mt][nt][rr] = 0.f;
    };

    auto mfma_layer = [&](int layer) {
        #pragma unroll
        for (int kt = 0; kt < 2; ++kt) {
            bf16x8 ah[2], al[2];
            #pragma unroll
            for (int mt = 0; mt < 2; ++mt) {
                f32x4 a0, a1;
                if (layer == 4) {           // A from global h
                    long nr = node0 + wrow0 + mt * 16 + c15; if (nr >= N) nr = N - 1;
                    const f32x4* p = (const f32x4*)(h + nr * 64 + kt * 32 + g * 8);
                    a0 = p[0];
                    a1 = p[1];
                } else {
                    int row = wrow0 + mt * 16 + c15;
                    int cb  = kt * 128 + g * 32;
                    a0 = *(const f32x4*)(lds + swz(row, cb));
                    a1 = *(const f32x4*)(lds + swz(row, cb + 16));
                }
                split8(a0, a1, ah[mt], al[mt]);
            }
            __builtin_amdgcn_s_setprio(1);
            #pragma unroll
            for (int nt = 0; nt < 4; ++nt) {
                int fo = ((layer * 8 + kt * 4 + nt) * 64 + lane) * 8;
                bf16x8 bh = *(const bf16x8*)(whi + fo);
                bf16x8 bl = *(const bf16x8*)(wlo + fo);
                #pragma unroll
                for (int mt = 0; mt < 2; ++mt) {
                    acc[mt][nt] = __builtin_amdgcn_mfma_f32_16x16x32_bf16(ah[mt], bh, acc[mt][nt], 0, 0, 0);
                    acc[mt][nt] = __builtin_amdgcn_mfma_f32_16x16x32_bf16(ah[mt], bl, acc[mt][nt], 0, 0, 0);
                    acc[mt][nt] = __builtin_amdgcn_mfma_f32_16x16x32_bf16(al[mt], bh, acc[mt][nt], 0, 0, 0);
                }
            }
            __builtin_amdgcn_s_setprio(0);
        }
    };

    auto writeback = [&](bool relu) {
        #pragma unroll
        for (int mt = 0; mt < 2; ++mt)
            #pragma unroll
            for (int nt = 0; nt < 4; ++nt)
                #pragma unroll
                for (int rr = 0; rr < 4; ++rr) {
                    int row  = wrow0 + mt * 16 + g * 4 + rr;
                    int colb = (nt * 16 + c15) * 4;
                    float v = acc[mt][nt][rr];
                    if (relu) v = fmaxf(v, 0.f);
                    *(float*)(lds + swz(row, colb)) = v;
                }
    };

    auto store_global = [&](float* __restrict__ out) {
        #pragma unroll
        for (int mt = 0; mt < 2; ++mt)
            #pragma unroll
            for (int nt = 0; nt < 4; ++nt)
                #pragma unroll
                for (int rr = 0; rr < 4; ++rr) {
                    long nr = node0 + wrow0 + mt * 16 + g * 4 + rr; if (nr >= N) nr = N - 1;
                    out[nr * 64 + nt * 16 + c15] = acc[mt][nt][rr];
                }
    };

    // L1: t1 = relu(h @ Wh1)
    zacc(); mfma_layer(4); writeback(true);
    // L2: z_h = t1 @ Wh2
    zacc(); mfma_layer(5);

    // as = z_h . Wa[64:128], ad = z_h . Wa[128:192]
    #pragma unroll
    for (int mt = 0; mt < 2; ++mt) {
        float ps[4], pd[4];
        #pragma unroll
        for (int rr = 0; rr < 4; ++rr) {
            ps[rr] = acc[mt][0][rr] * was[0] + acc[mt][1][rr] * was[1]
                   + acc[mt][2][rr] * was[2] + acc[mt][3][rr] * was[3];
            pd[rr] = acc[mt][0][rr] * wad[0] + acc[mt][1][rr] * wad[1]
                   + acc[mt][2][rr] * wad[2] + acc[mt][3][rr] * wad[3];
        }
        #pragma unroll
        for (int off = 1; off < 16; off <<= 1)
            #pragma unroll
            for (int rr = 0; rr < 4; ++rr) {
                ps[rr] += __shfl_xor(ps[rr], off);
                pd[rr] += __shfl_xor(pd[rr], off);
            }
        if (c15 == 0) {
            #pragma unroll
            for (int rr = 0; rr < 4; ++rr) {
                long nr = node0 + wrow0 + mt * 16 + g * 4 + rr; if (nr >= N) nr = N - 1;
                as_[nr] = ps[rr];
                ad_[nr] = pd[rr];
            }
        }
    }
    store_global(z_h);
    writeback(false);   // z_h -> LDS for L3/L4

    // L3: u_s = z_h @ Wp1[64:128]
    zacc(); mfma_layer(6); store_global(u_s);
    // L4: u_d = z_h @ Wp1[128:192]  (LDS still holds z_h)
    zacc(); mfma_layer(7); store_global(u_d);
}

// ---- edge pipeline: split-bf16 MFMA chain, wave-private rows, no barriers.
// uv/asv gathers prefetched at start (R4-proven). No fused CSR fill (R7 showed
// the fused atomics cost ~60µs in-kernel). Streaming data (e in, eproj/abuf
// out) uses nontemporal accesses to keep u_s/u_d resident in L2/L3.
__global__ __launch_bounds__(256) void edge_mfma(
    const float* __restrict__ e, const int* __restrict__ src, const int* __restrict__ dst,
    const float* __restrict__ u_s, const float* __restrict__ u_d,
    const float* __restrict__ as_, const float* __restrict__ ad_,
    const unsigned short* __restrict__ whi, const unsigned short* __restrict__ wlo,
    const float* __restrict__ Wa, const float* __restrict__ bp1, const float* __restrict__ bp2,
    float* __restrict__ eproj, float* __restrict__ abuf, int E)
{
    __shared__ float act[BM * 64];
    char* lds = (char*)act;
    const int lane  = threadIdx.x & 63;
    const int wave  = threadIdx.x >> 6;
    const int wrow0 = wave * 32;
    const long edge0 = (long)blockIdx.x * BM;
    const int g   = lane >> 4;
    const int c15 = lane & 15;

    int sn[2][4], dn[2][4];
    #pragma unroll
    for (int mt = 0; mt < 2; ++mt)
        #pragma unroll
        for (int rr = 0; rr < 4; ++rr) {
            long er = edge0 + wrow0 + mt * 16 + g * 4 + rr; if (er >= E) er = E - 1;
            sn[mt][rr] = src[er]; dn[mt][rr] = dst[er];
        }

    float waf[4], b1f[4], b2f[4];
    #pragma unroll
    for (int nt = 0; nt < 4; ++nt) {
        waf[nt] = Wa[nt * 16 + c15];
        b1f[nt] = bp1[nt * 16 + c15];
        b2f[nt] = bp2[nt * 16 + c15];
    }

    // prefetch per-edge gathers early (consumed at attention / L3 accumulate)
    float uv[2][4][4], asv[2][4];
    #pragma unroll
    for (int mt = 0; mt < 2; ++mt)
        #pragma unroll
        for (int rr = 0; rr < 4; ++rr) {
            const float* us = u_s + (size_t)sn[mt][rr] * DIM;
            const float* ud = u_d + (size_t)dn[mt][rr] * DIM;
            #pragma unroll
            for (int nt = 0; nt < 4; ++nt)
                uv[mt][nt][rr] = us[nt * 16 + c15] + ud[nt * 16 + c15] + b1f[nt];
            asv[mt][rr] = as_[sn[mt][rr]] + ad_[dn[mt][rr]];
        }

    f32x4 acc[2][4];
    auto zacc = [&]() {
        #pragma unroll
        for (int mt = 0; mt < 2; ++mt)
            #pragma unroll
            for (int nt = 0; nt < 4; ++nt)
                #pragma unroll
                for (int rr = 0; rr < 4; ++rr) acc[mt][nt][rr] = 0.f;
    };

    auto mfma_layer = [&](int layer) {
        #pragma unroll
        for (int kt = 0; kt < 2; ++kt) {
            bf16x8 ah[2], al[2];
            #pragma unroll
            for (int mt = 0; mt < 2; ++mt) {
                f32x4 a0, a1;
                if (layer == 0) {   // streaming read-once: nontemporal
                    long er = edge0 + wrow0 + mt * 16 + c15; if (er >= E) er = E - 1;
                    const f32x4* p = (const f32x4*)(e + er * 64 + kt * 32 + g * 8);
                    a0 = __builtin_nontemporal_load(p);
                    a1 = __builtin_nontemporal_load(p + 1);
                } else {
                    int row = wrow0 + mt * 16 + c15;
                    int cb  = kt * 128 + g * 32;
                    a0 = *(const f32x4*)(lds + swz(row, cb));
                    a1 = *(const f32x4*)(lds + swz(row, cb + 16));
                }
                split8(a0, a1, ah[mt], al[mt]);
            }
            __builtin_amdgcn_s_setprio(1);
            #pragma unroll
            for (int nt = 0; nt < 4; ++nt) {
                int fo = ((layer * 8 + kt * 4 + nt) * 64 + lane) * 8;
                bf16x8 bh = *(const bf16x8*)(whi + fo);
                bf16x8 bl = *(const bf16x8*)(wlo + fo);
                #pragma unroll
                for (int mt = 0; mt < 2; ++mt) {
                    acc[mt][nt] = __builtin_amdgcn_mfma_f32_16x16x32_bf16(ah[mt], bh, acc[mt][nt], 0, 0, 0);
                    acc[mt][nt] = __builtin_amdgcn_mfma_f32_16x16x32_bf16(ah[mt], bl, acc[mt][nt], 0, 0, 0);
                    acc[mt][nt] = __builtin_amdgcn_mfma_f32_16x16x32_bf16(al[mt], bh, acc[mt][nt], 0, 0, 0);
                }
            }
            __builtin_amdgcn_s_setprio(0);
        }
    };

    auto writeback = [&](bool relu) {
        #pragma unroll
        for (int mt = 0; mt < 2; ++mt)
            #pragma unroll
            for (int nt = 0; nt < 4; ++nt)
                #pragma unroll
                for (int rr = 0; rr < 4; ++rr) {
                    int row  = wrow0 + mt * 16 + g * 4 + rr;
                    int colb = (nt * 16 + c15) * 4;
                    float v = acc[mt][nt][rr];
                    if (relu) v = fmaxf(v, 0.f);
                    *(float*)(lds + swz(row, colb)) = v;
                }
    };

    // L1: t1 = relu(e @ We1)
    zacc(); mfma_layer(0); writeback(true);
    // L2: z_e = t1 @ We2
    zacc(); mfma_layer(1);

    // attention: ae = z_e . Wa[0:64]; a = relu(ae + as[src] + ad[dst])
    #pragma unroll
    for (int mt = 0; mt < 2; ++mt) {
        float part[4];
        #pragma unroll
        for (int rr = 0; rr < 4; ++rr)
            part[rr] = acc[mt][0][rr] * waf[0] + acc[mt][1][rr] * waf[1]
                     + acc[mt][2][rr] * waf[2] + acc[mt][3][rr] * waf[3];
        #pragma unroll
        for (int off = 1; off < 16; off <<= 1)
            #pragma unroll
            for (int rr = 0; rr < 4; ++rr) part[rr] += __shfl_xor(part[rr], off);
        if (c15 == 0) {
            #pragma unroll
            for (int rr = 0; rr < 4; ++rr) {
                long er = edge0 + wrow0 + mt * 16 + g * 4 + rr; if (er >= E) er = E - 1;
                __builtin_nontemporal_store(fmaxf(part[rr] + asv[mt][rr], 0.f), abuf + er);
            }
        }
    }
    writeback(false);

    // L3: t2 = relu(z_e @ Wp1top + uv + bp1)   (uv prefetched at start)
    zacc(); mfma_layer(2);
    #pragma unroll
    for (int mt = 0; mt < 2; ++mt)
        #pragma unroll
        for (int nt = 0; nt < 4; ++nt)
            #pragma unroll
            for (int rr = 0; rr < 4; ++rr)
                acc[mt][nt][rr] += uv[mt][nt][rr];
    writeback(true);

    // L4: eproj = relu(t2 @ Wp2 + bp2)  — streaming write-once: nontemporal
    zacc(); mfma_layer(3);
    #pragma unroll
    for (int mt = 0; mt < 2; ++mt)
        #pragma unroll
        for (int nt = 0; nt < 4; ++nt)
            #pragma unroll
            for (int rr = 0; rr < 4; ++rr) {
                long er = edge0 + wrow0 + mt * 16 + g * 4 + rr; if (er >= E) er = E - 1;
                __builtin_nontemporal_store(fmaxf(acc[mt][nt][rr] + b2f[nt], 0.f),
                                            eproj + er * 64 + nt * 16 + c15);
            }
}

// ---- CSR build ----
__global__ __launch_bounds__(256) void k_hist(
    const int* __restrict__ dst, int* __restrict__ cnt, int E)
{
    int i = blockIdx.x * 256 + threadIdx.x;
    if (i < E) atomicAdd(&cnt[dst[i]], 1);
}

__global__ __launch_bounds__(256) void k_scan1(
    const int* __restrict__ cnt, int* __restrict__ ofs, int* __restrict__ bsum, int N)
{
    __shared__ int sm[256];
    int t = threadIdx.x, i = blockIdx.x * 256 + t;
    int v = (i < N) ? cnt[i] : 0;
    sm[t] = v;
    __syncthreads();
    #pragma unroll
    for (int off = 1; off < 256; off <<= 1) {
        int tmp = (t >= off) ? sm[t - off] : 0;
        __syncthreads();
        sm[t] += tmp;
        __syncthreads();
    }
    if (i < N) ofs[i] = sm[t] - v;
    if (t == 255) bsum[blockIdx.x] = sm[255];
}

__global__ __launch_bounds__(256) void k_scan2(int* __restrict__ bsum, int NB)
{
    __shared__ int sm[256];
    int t = threadIdx.x;
    int v = (t < NB) ? bsum[t] : 0;
    sm[t] = v;
    __syncthreads();
    #pragma unroll
    for (int off = 1; off < 256; off <<= 1) {
        int tmp = (t >= off) ? sm[t - off] : 0;
        __syncthreads();
        sm[t] += tmp;
        __syncthreads();
    }
    if (t < NB) bsum[t] = sm[t] - v;   // exclusive
}

__global__ __launch_bounds__(256) void k_scan3(
    int* __restrict__ ofs, int* __restrict__ cursor,
    const int* __restrict__ bsum, int N)
{
    int i = blockIdx.x * 256 + threadIdx.x;
    if (i < N) {
        int o = ofs[i] + bsum[blockIdx.x];
        ofs[i] = o;
        cursor[i] = o;
    }
}

__global__ __launch_bounds__(256) void k_fill(
    const int* __restrict__ dst, int* __restrict__ cursor, int* __restrict__ eidx, int E)
{
    int i = blockIdx.x * 256 + threadIdx.x;
    if (i < E) {
        int p = atomicAdd(&cursor[dst[i]], 1);
        eidx[p] = i;
    }
}

// ---- fused segment softmax + weighted gather: 1 wave/node.
// Fast path (deg<=64): lane-parallel loads; gather loop runs a UNIFORM trip
// count so every __shfl source lane is active.
__global__ __launch_bounds__(256) void k_aggregate(
    const float* __restrict__ abuf, const int* __restrict__ eidx,
    const int* __restrict__ ofs, const int* __restrict__ cnt,
    const int* __restrict__ src, const float* __restrict__ z_h,
    float* __restrict__ hout, int N)
{
    int wid  = (blockIdx.x * 256 + threadIdx.x) >> 6;
    int lane = threadIdx.x & 63;
    if (wid >= N) return;
    int grp = lane >> 4, c15 = lane & 15;

    int begin = ofs[wid];
    int deg   = cnt[wid];

    float4 acc = make_float4(0.f, 0.f, 0.f, 0.f);
    float inv_s;

    if (deg <= 64) {
        float a = 0.f; int sidx = 0;
        if (lane < deg) {
            int eid = eidx[begin + lane];
            a    = abuf[eid];
            sidx = src[eid];
        }
        float m = a;
        #pragma unroll
        for (int off = 32; off; off >>= 1) m = fmaxf(m, __shfl_xor(m, off));

        float ex = (lane < deg) ? __expf(a - m) : 0.f;
        float s = ex;
        #pragma unroll
        for (int off = 32; off; off >>= 1) s += __shfl_xor(s, off);
        inv_s = 1.0f / fmaxf(s, 1e-9f);

        int trips = (deg + 3) >> 2;
        for (int i = 0; i < trips; ++i) {
            int k = grp + 4 * i;
            float w  = __shfl(ex,   k & 63);
            int   sk = __shfl(sidx, k & 63);
            if (k < deg) {
                const float4 v = *(const float4*)(z_h + (size_t)sk * DIM + c15 * 4);
                acc.x = fmaf(w, v.x, acc.x);
                acc.y = fmaf(w, v.y, acc.y);
                acc.z = fmaf(w, v.z, acc.z);
                acc.w = fmaf(w, v.w, acc.w);
            }
        }
    } else {
        float m = 0.f;
        for (int k = lane; k < deg; k += 64) m = fmaxf(m, abuf[eidx[begin + k]]);
        #pragma unroll
        for (int off = 32; off; off >>= 1) m = fmaxf(m, __shfl_xor(m, off));

        float s = 0.f;
        for (int k = lane; k < deg; k += 64) s += __expf(abuf[eidx[begin + k]] - m);
        #pragma unroll
        for (int off = 32; off; off >>= 1) s += __shfl_xor(s, off);
        inv_s = 1.0f / fmaxf(s, 1e-9f);

        for (int k = grp; k < deg; k += 4) {
            int eid = eidx[begin + k];
            float w = __expf(abuf[eid] - m);
            const float4 v = *(const float4*)(z_h + (size_t)src[eid] * DIM + c15 * 4);
            acc.x = fmaf(w, v.x, acc.x);
            acc.y = fmaf(w, v.y, acc.y);
            acc.z = fmaf(w, v.z, acc.z);
            acc.w = fmaf(w, v.w, acc.w);
        }
    }

    #pragma unroll
    for (int off = 16; off <= 32; off <<= 1) {
        acc.x += __shfl_xor(acc.x, off);
        acc.y += __shfl_xor(acc.y, off);
        acc.z += __shfl_xor(acc.z, off);
        acc.w += __shfl_xor(acc.w, off);
    }
    if (grp == 0) {
        float4 r = make_float4(fmaxf(acc.x * inv_s, 0.f), fmaxf(acc.y * inv_s, 0.f),
                               fmaxf(acc.z * inv_s, 0.f), fmaxf(acc.w * inv_s, 0.f));
        *(float4*)(hout + (size_t)wid * DIM + c15 * 4) = r;
    }
}

extern "C" void kernel_launch(void* const* d_in, const int* in_sizes, int n_in,
                              void* d_out, int out_size, void* d_ws, size_t ws_size,
                              hipStream_t stream)
{
    const float* h   = (const float*)d_in[0];
    const float* e   = (const float*)d_in[1];
    const int*   src = (const int*)d_in[2];
    const int*   dst = (const int*)d_in[3];
    const float* Wh1 = (const float*)d_in[4];
    const float* Wh2 = (const float*)d_in[5];
    const float* We1 = (const float*)d_in[6];
    const float* We2 = (const float*)d_in[7];
    const float* Wp1 = (const float*)d_in[8];
    const float* bp1 = (const float*)d_in[9];
    const float* Wp2 = (const float*)d_in[10];
    const float* bp2 = (const float*)d_in[11];
    const float* Wa  = (const float*)d_in[12];

    const int N = in_sizes[0] / DIM;
    const int E = in_sizes[1] / DIM;

    float* ws   = (float*)d_ws;
    float* z_h  = ws;  ws += (size_t)N * DIM;
    float* u_s  = ws;  ws += (size_t)N * DIM;
    float* u_d  = ws;  ws += (size_t)N * DIM;
    float* as_  = ws;  ws += N;
    float* ad_  = ws;  ws += N;
    float* abuf = ws;  ws += E;
    int* cnt    = (int*)ws;  ws += N;
    int* ofs    = (int*)ws;  ws += N;
    int* cursor = (int*)ws;  ws += N;
    int* eidx   = (int*)ws;  ws += E;
    int* bsum   = (int*)ws;  ws += 256;
    unsigned short* whi = (unsigned short*)ws;  ws += 32768 / 2;
    unsigned short* wlo = (unsigned short*)ws;  ws += 32768 / 2;

    float* hout  = (float*)d_out;
    float* eproj = hout + (size_t)N * DIM;

    const int NB = (N + 255) / 256;   // N=50000 -> 196 <= 256

    hipMemsetAsync(cnt, 0, (size_t)N * sizeof(int), stream);

    k_prep<<<128, 256, 0, stream>>>(We1, We2, Wp1, Wp2, Wh1, Wh2, whi, wlo);

    k_hist<<<(E + 255) / 256, 256, 0, stream>>>(dst, cnt, E);
    k_scan1<<<NB, 256, 0, stream>>>(cnt, ofs, bsum, N);
    k_scan2<<<1, 256, 0, stream>>>(bsum, NB);
    k_scan3<<<NB, 256, 0, stream>>>(ofs, cursor, bsum, N);
    k_fill<<<(E + 255) / 256, 256, 0, stream>>>(dst, cursor, eidx, E);

    node_mfma<<<(N + BM - 1) / BM, 256, 0, stream>>>(
        h, whi, wlo, Wa, z_h, u_s, u_d, as_, ad_, N);

    edge_mfma<<<(E + BM - 1) / BM, 256, 0, stream>>>(
        e, src, dst, u_s, u_d, as_, ad_, whi, wlo, Wa, bp1, bp2,
        eproj, abuf, E);

    k_aggregate<<<((N * 64) + 255) / 256, 256, 0, stream>>>(
        abuf, eidx, ofs, cnt, src, z_h, hout, N);
}